// Round 1
// baseline (552.808 us; speedup 1.0000x reference)
//
#include <hip/hip_runtime.h>
#include <math.h>

// ---------------- problem constants ----------------
#define SLEN   1024
#define NGRP   4
#define NHEAD  16
#define HPGRP  4
#define DKV    64
#define SCMP   63     // (1024-32)/16+1
#define NBLK   16
#define NSELK  8
#define WWIN   512
#define SCALEF 0.125f // 1/sqrt(64)

struct Ptr6 { const float* w[6]; };

// ---------------- GEMM: C[M][N] = A[M][K] @ W[N][K]^T ----------------
__device__ __forceinline__ void gemm_body(
    const float* __restrict__ A, const float* __restrict__ W, float* __restrict__ C,
    int N, int K, int bm, int bn, int tid)
{
  __shared__ float As[16][65];
  __shared__ float Bs[16][65];
  const int tx = tid & 15, ty = tid >> 4;
  float acc[4][4];
#pragma unroll
  for (int i = 0; i < 4; ++i)
#pragma unroll
    for (int j = 0; j < 4; ++j) acc[i][j] = 0.f;

  for (int k0 = 0; k0 < K; k0 += 16) {
#pragma unroll
    for (int i0 = 0; i0 < 4; ++i0) {
      int i = tid + i0 * 256;
      int r = i >> 4, c = i & 15;
      As[c][r] = A[(size_t)(bm + r) * K + (k0 + c)];
      Bs[c][r] = W[(size_t)(bn + r) * K + (k0 + c)];
    }
    __syncthreads();
#pragma unroll
    for (int kk = 0; kk < 16; ++kk) {
      float a[4], b[4];
#pragma unroll
      for (int i = 0; i < 4; ++i) a[i] = As[kk][ty * 4 + i];
#pragma unroll
      for (int j = 0; j < 4; ++j) b[j] = Bs[kk][tx * 4 + j];
#pragma unroll
      for (int i = 0; i < 4; ++i)
#pragma unroll
        for (int j = 0; j < 4; ++j) acc[i][j] += a[i] * b[j];
    }
    __syncthreads();
  }
#pragma unroll
  for (int i = 0; i < 4; ++i)
#pragma unroll
    for (int j = 0; j < 4; ++j)
      C[(size_t)(bm + ty * 4 + i) * N + (bn + tx * 4 + j)] = acc[i][j];
}

__global__ __launch_bounds__(256) void gemm_xwT(
    const float* __restrict__ A, const float* __restrict__ W, float* __restrict__ C,
    int N, int K)
{
  gemm_body(A, W, C, N, K, blockIdx.y * 64, blockIdx.x * 64, threadIdx.x);
}

__global__ __launch_bounds__(256) void gemm_kv6(
    const float* __restrict__ A, Ptr6 p6, float* __restrict__ Cbase)
{
  const float* W = p6.w[blockIdx.z];
  float* C = Cbase + (size_t)blockIdx.z * (SLEN * 256);
  gemm_body(A, W, C, 256, 1024, blockIdx.y * 64, blockIdx.x * 64, threadIdx.x);
}

// ---------------- RoPE (in place, pos = row index s) ----------------
__global__ void rope_q_kernel(float* __restrict__ buf)  // [S][16*64]
{
  const int s = blockIdx.x;
  const int t = threadIdx.x;          // 512 = 16 chunks * 32
  const int c = t >> 5, d = t & 31;
  float* p = buf + (size_t)s * 1024 + c * 64;
  const float inv = powf(10000.f, -(float)d * (1.f / 32.f));
  float sn, cs;
  sincosf((float)s * inv, &sn, &cs);
  const float x1 = p[d], x2 = p[d + 32];
  p[d]      = x1 * cs - x2 * sn;
  p[d + 32] = x1 * sn + x2 * cs;
}

__global__ void rope_k_kernel(float* __restrict__ kvbase) // ksel/kwin/kcmp via blockIdx.y
{
  const int s = blockIdx.x;
  const int which = blockIdx.y;       // 0->ksel, 1->kwin, 2->kcmp (offsets 0,2,4)
  const int t = threadIdx.x;          // 128 = 4 chunks * 32
  const int c = t >> 5, d = t & 31;
  float* p = kvbase + (size_t)which * 2 * (SLEN * 256) + (size_t)s * 256 + c * 64;
  const float inv = powf(10000.f, -(float)d * (1.f / 32.f));
  float sn, cs;
  sincosf((float)s * inv, &sn, &cs);
  const float x1 = p[d], x2 = p[d + 32];
  p[d]      = x1 * cs - x2 * sn;
  p[d + 32] = x1 * sn + x2 * cs;
}

// ---------------- cmp pooling: mean over 32-token windows ----------------
__global__ __launch_bounds__(64) void pool_kernel(
    const float* __restrict__ k_cmp, const float* __restrict__ v_cmp,
    float* __restrict__ Kc, float* __restrict__ Vc)
{
  const int c = blockIdx.x;   // 0..62
  const int g = blockIdx.y;   // 0..3
  const int d = threadIdx.x;  // 0..63
  float ak = 0.f, av = 0.f;
  for (int j = 0; j < 32; ++j) {
    const size_t off = (size_t)(c * 16 + j) * 256 + g * 64 + d;
    ak += k_cmp[off];
    av += v_cmp[off];
  }
  Kc[(size_t)(g * SCMP + c) * 64 + d] = ak * (1.f / 32.f);
  Vc[(size_t)(g * SCMP + c) * 64 + d] = av * (1.f / 32.f);
}

// ---------------- gating MLP ----------------
__global__ __launch_bounds__(64) void gate_kernel(
    const float* __restrict__ q, const float* __restrict__ g1w, const float* __restrict__ g1b,
    const float* __restrict__ g2w, const float* __restrict__ g2b, float* __restrict__ gates)
{
  const int s = blockIdx.x, g = blockIdx.y;
  const int t = threadIdx.x;
  __shared__ float qg[64], h1[32];
  const float* qb = q + (size_t)(s * 16 + g * 4) * 64;
  qg[t] = (qb[t] + qb[64 + t] + qb[128 + t] + qb[192 + t]) * 0.25f;
  __syncthreads();
  if (t < 32) {
    float a = g1b[t];
    for (int d = 0; d < 64; ++d) a += qg[d] * g1w[t * 64 + d];
    h1[t] = a / (1.f + expf(-a));   // silu
  }
  __syncthreads();
  if (t == 0) {
    float gl[3];
    for (int r = 0; r < 3; ++r) {
      float a = g2b[r];
      for (int j = 0; j < 32; ++j) a += h1[j] * g2w[r * 32 + j];
      gl[r] = a;  // TAU = 1
    }
    const float m1 = fmaxf(gl[0], fmaxf(gl[1], gl[2]));
    const float e0 = expf(gl[0] - m1), e1 = expf(gl[1] - m1), e2 = expf(gl[2] - m1);
    const float inv = 1.f / (e0 + e1 + e2);
    float p0 = e0 * inv, p1 = e1 * inv, p2 = e2 * inv;
    int am = 0; float best = gl[0];
    if (gl[1] > best) { best = gl[1]; am = 1; }
    if (gl[2] > best) { best = gl[2]; am = 2; }
    float second = -INFINITY;
    for (int r = 0; r < 3; ++r) if (r != am) second = fmaxf(second, gl[r]);
    if (best - second > 50.f) { p0 = (am == 0) ? 1.f : 0.f; p1 = (am == 1) ? 1.f : 0.f; p2 = (am == 2) ? 1.f : 0.f; }
    float* o = gates + (size_t)(s * 4 + g) * 3;
    o[0] = p0; o[1] = p1; o[2] = p2;
  }
}

// ---------------- fused NSA attention: one block per (s, g), wave = head ----------------
__global__ __launch_bounds__(256) void attn_kernel(
    const float* __restrict__ q,
    const float* __restrict__ k_sel, const float* __restrict__ v_sel,
    const float* __restrict__ k_win, const float* __restrict__ v_win,
    const float* __restrict__ Kc,    const float* __restrict__ Vc,
    const float* __restrict__ gates, float* __restrict__ O)
{
  const int s = blockIdx.x;
  const int g = blockIdx.y;
  const int tid = threadIdx.x;
  const int wave = tid >> 6;     // head within group
  const int lane = tid & 63;

  __shared__ float q_s[4][64];
  __shared__ float kt[64][65];       // +1 pad: per-lane row dot = 2-way bank (free)
  __shared__ float pc[4][64];
  __shared__ float p_lds[4][8][64];  // wave-private by head
  __shared__ float ps4[4][16];
  __shared__ float lg[16];
  __shared__ int   selblk[8];
  __shared__ int   nsel_s;

  q_s[wave][lane] = q[(size_t)(s * 16 + g * 4 + wave) * 64 + lane];
  for (int i = tid; i < SCMP * 64; i += 256) {
    const int r = i >> 6, c = i & 63;
    kt[r][c] = Kc[(size_t)(g * SCMP + r) * 64 + c];
  }
  __syncthreads();

  // ---- cmp branch: lane = compressed index c ----
  const int nv = (s >= 31) ? min(SCMP, ((s - 31) >> 4) + 1) : 0;
  float scc = -INFINITY;
  if (lane < nv) {
    float a = 0.f;
    for (int d = 0; d < 64; ++d) a += q_s[wave][d] * kt[lane][d];
    scc = a * SCALEF;
  }
  float mc = scc;
#pragma unroll
  for (int o = 32; o; o >>= 1) mc = fmaxf(mc, __shfl_xor(mc, o));
  const float pcv = (lane < nv) ? expf(scc - mc) : 0.f;
  float sumc = pcv;
#pragma unroll
  for (int o = 32; o; o >>= 1) sumc += __shfl_xor(sumc, o);
  pc[wave][lane] = (nv > 0) ? (pcv / sumc) : 0.f;
  __syncthreads();

  // O_cmp: lane = d
  float o_cmp = 0.f;
  for (int c = 0; c < nv; ++c)
    o_cmp += pc[wave][c] * Vc[(size_t)(g * SCMP + c) * 64 + lane];

  // per-head partial p_slc (M_MAP applied inline)
  if (lane < 16) {
    float a = 0.f;
    for (int c = 0; c < nv; ++c) {
      const int lo_ = max(c * 16, lane * 64);
      const int hi_ = min(c * 16 + 32, lane * 64 + 64);
      if (hi_ > lo_) a += pc[wave][c] * (float)(hi_ - lo_) * (1.f / 32.f);
    }
    ps4[wave][lane] = a;
  }
  __syncthreads();

  // selection logits (wave 0)
  if (wave == 0 && lane < 16) {
    const float psl = ps4[0][lane] + ps4[1][lane] + ps4[2][lane] + ps4[3][lane];
    const bool causal = (lane << 6) <= s;
    const bool forced = (lane == 0) || (lane == (s >> 6));
    lg[lane] = causal ? (psl + (forced ? 1e6f : 0.f)) : -1e9f;
  }
  __syncthreads();

  // top-8 set, top_k tie-break = (value desc, index asc)
  if (wave == 0) {
    bool sel = false;
    if (lane < 16) {
      const float my = lg[lane];
      int rank = 0;
      for (int m2 = 0; m2 < 16; ++m2) {
        const float v = lg[m2];
        if (v > my || (v == my && m2 < lane)) ++rank;
      }
      sel = (rank < NSELK) && ((lane << 6) <= s);  // non-causal picks are fully masked anyway
    }
    const unsigned long long msk = __ballot(sel);
    if (sel) selblk[__popcll(msk & ((1ull << lane) - 1ull))] = lane;
    if (lane == 0) nsel_s = (int)__popcll(msk);
  }
  __syncthreads();
  const int nsel = nsel_s;   // >= 1 (block 0 forced+causal)

  // ---- selected-blocks branch ----
  float sc8[8];
#pragma unroll
  for (int j = 0; j < 8; ++j) sc8[j] = -INFINITY;
#pragma unroll
  for (int j = 0; j < 8; ++j) {
    if (j < nsel) {                 // uniform across block
      const int base = selblk[j] << 6;
      __syncthreads();              // previous kt readers done
      for (int i = tid; i < 1024; i += 256) {
        const int r = i >> 4, c4 = (i & 15) << 2;
        const float4 kv4 = *reinterpret_cast<const float4*>(
            &k_sel[(size_t)(base + r) * 256 + g * 64 + c4]);
        kt[r][c4 + 0] = kv4.x; kt[r][c4 + 1] = kv4.y;
        kt[r][c4 + 2] = kv4.z; kt[r][c4 + 3] = kv4.w;
      }
      __syncthreads();
      if (base + lane <= s) {
        float a = 0.f;
        for (int d = 0; d < 64; ++d) a += q_s[wave][d] * kt[lane][d];
        sc8[j] = a * SCALEF;
      }
    }
  }
  float mx = -INFINITY;
#pragma unroll
  for (int j = 0; j < 8; ++j) mx = fmaxf(mx, sc8[j]);
#pragma unroll
  for (int o = 32; o; o >>= 1) mx = fmaxf(mx, __shfl_xor(mx, o));
  float dsel = 0.f;
#pragma unroll
  for (int j = 0; j < 8; ++j) {
    const float p = expf(sc8[j] - mx);  // exp(-inf)=0 for masked/unused
    p_lds[wave][j][lane] = p;
    dsel += p;
  }
#pragma unroll
  for (int o = 32; o; o >>= 1) dsel += __shfl_xor(dsel, o);
  __syncthreads();

  float o_sel = 0.f;
#pragma unroll
  for (int j = 0; j < 8; ++j) {
    if (j < nsel) {
      const int base = selblk[j] << 6;
      const int lim = min(63, s - base);
      for (int l = 0; l <= lim; ++l)
        o_sel += p_lds[wave][j][l] * v_sel[(size_t)(base + l) * 256 + g * 64 + lane];
    }
  }
  o_sel /= dsel;

  // ---- sliding-window branch ----
  const int lo = (s >= WWIN) ? (s - WWIN + 1) : 0;
  const int nch = ((s - lo + 1) + 63) >> 6;
#pragma unroll
  for (int j = 0; j < 8; ++j) sc8[j] = -INFINITY;
#pragma unroll
  for (int j = 0; j < 8; ++j) {
    if (j < nch) {                  // uniform
      const int base = lo + (j << 6);
      __syncthreads();
      for (int i = tid; i < 1024; i += 256) {
        const int r = i >> 4, c4 = (i & 15) << 2;
        const float4 kv4 = *reinterpret_cast<const float4*>(
            &k_win[(size_t)(base + r) * 256 + g * 64 + c4]);
        kt[r][c4 + 0] = kv4.x; kt[r][c4 + 1] = kv4.y;
        kt[r][c4 + 2] = kv4.z; kt[r][c4 + 3] = kv4.w;
      }
      __syncthreads();
      if (base + lane <= s) {
        float a = 0.f;
        for (int d = 0; d < 64; ++d) a += q_s[wave][d] * kt[lane][d];
        sc8[j] = a * SCALEF;
      }
    }
  }
  float mw = -INFINITY;
#pragma unroll
  for (int j = 0; j < 8; ++j) mw = fmaxf(mw, sc8[j]);
#pragma unroll
  for (int o = 32; o; o >>= 1) mw = fmaxf(mw, __shfl_xor(mw, o));
  float dwin = 0.f;
#pragma unroll
  for (int j = 0; j < 8; ++j) {
    const float p = expf(sc8[j] - mw);
    p_lds[wave][j][lane] = p;
    dwin += p;
  }
#pragma unroll
  for (int o = 32; o; o >>= 1) dwin += __shfl_xor(dwin, o);
  __syncthreads();

  float o_win = 0.f;
#pragma unroll
  for (int j = 0; j < 8; ++j) {
    if (j < nch) {
      const int base = lo + (j << 6);
      const int lim = min(63, s - base);
      for (int l = 0; l <= lim; ++l)
        o_win += p_lds[wave][j][l] * v_win[(size_t)(base + l) * 256 + g * 64 + lane];
    }
  }
  o_win /= dwin;

  // ---- gate combine, write O[s][g*4+wave][lane] ----
  const float* pg = gates + (size_t)(s * 4 + g) * 3;
  O[(size_t)(s * 16 + g * 4 + wave) * 64 + lane] =
      pg[0] * o_cmp + pg[1] * o_sel + pg[2] * o_win;
}

// ---------------- launch ----------------
extern "C" void kernel_launch(void* const* d_in, const int* in_sizes, int n_in,
                              void* d_out, int out_size, void* d_ws, size_t ws_size,
                              hipStream_t stream) {
  const float* x      = (const float*)d_in[0];
  const float* wq     = (const float*)d_in[1];
  const float* wk_sel = (const float*)d_in[2];
  const float* wv_sel = (const float*)d_in[3];
  const float* wk_win = (const float*)d_in[4];
  const float* wv_win = (const float*)d_in[5];
  const float* wk_cmp = (const float*)d_in[6];
  const float* wv_cmp = (const float*)d_in[7];
  const float* w_out  = (const float*)d_in[8];
  const float* g1w    = (const float*)d_in[9];
  const float* g1b    = (const float*)d_in[10];
  const float* g2w    = (const float*)d_in[11];
  const float* g2b    = (const float*)d_in[12];

  float* ws = (float*)d_ws;
  // workspace layout (floats): total ~3.72M floats = ~14.9 MB
  float* q     = ws;                       // 1048576
  float* kv    = ws + 1048576;             // 6 * 262144
  float* ksel  = kv;
  float* vsel  = kv + 1 * 262144;
  float* kwin  = kv + 2 * 262144;
  float* vwin  = kv + 3 * 262144;
  float* kcmp  = kv + 4 * 262144;
  float* vcmp  = kv + 5 * 262144;
  float* Kc    = kv + 6 * 262144;          // 16128
  float* Vc    = Kc + 16128;               // 16128
  float* gts   = Vc + 16128;               // 12288
  float* Obuf  = gts + 12288;              // 1048576

  // projections
  gemm_xwT<<<dim3(16, 16), 256, 0, stream>>>(x, wq, q, 1024, 1024);
  Ptr6 p6 = {{ wk_sel, wv_sel, wk_win, wv_win, wk_cmp, wv_cmp }};
  gemm_kv6<<<dim3(4, 16, 6), 256, 0, stream>>>(x, p6, kv);

  // rope
  rope_q_kernel<<<1024, 512, 0, stream>>>(q);
  rope_k_kernel<<<dim3(1024, 3), 128, 0, stream>>>(kv);

  // compressed pooling
  pool_kernel<<<dim3(63, 4), 64, 0, stream>>>(kcmp, vcmp, Kc, Vc);

  // gates (uses roped q)
  gate_kernel<<<dim3(1024, 4), 64, 0, stream>>>(q, g1w, g1b, g2w, g2b, gts);

  // fused NSA attention
  attn_kernel<<<dim3(1024, 4), 256, 0, stream>>>(q, ksel, vsel, kwin, vwin, Kc, Vc, gts, Obuf);

  // output projection
  gemm_xwT<<<dim3(16, 16), 256, 0, stream>>>(Obuf, w_out, (float*)d_out, 1024, 1024);
}

// Round 2
// 327.865 us; speedup vs baseline: 1.6861x; 1.6861x over previous
//
#include <hip/hip_runtime.h>
#include <math.h>

// ---------------- problem constants ----------------
#define SLEN   1024
#define NGRP   4
#define NHEAD  16
#define HPGRP  4
#define DKV    64
#define SCMP   63     // (1024-32)/16+1
#define NBLK   16
#define NSELK  8
#define WWIN   512
#define SCALEF 0.125f // 1/sqrt(64)

typedef __attribute__((ext_vector_type(4))) float f32x4;
typedef __attribute__((ext_vector_type(8))) short bf16x8;

// ---------------- f32 -> bf16 (RNE) batched convert ----------------
__device__ __forceinline__ unsigned short f2bf(float f) {
  unsigned u = __float_as_uint(f);
  u += 0x7FFFu + ((u >> 16) & 1u);
  return (unsigned short)(u >> 16);
}
__device__ __forceinline__ unsigned pack2(float a, float b) {
  return (unsigned)f2bf(a) | ((unsigned)f2bf(b) << 16);
}

struct ConvJobs {
  const float* src[9];
  unsigned* dst[9];
  int n4[9];   // element count / 4
  int cnt;
};

__global__ __launch_bounds__(256) void conv_f32_bf16(ConvJobs jb) {
  const int stride = gridDim.x * blockDim.x;
  for (int t = 0; t < jb.cnt; ++t) {
    const float4* s = (const float4*)jb.src[t];
    uint2* d = (uint2*)jb.dst[t];
    const int n4 = jb.n4[t];
    for (int i = blockIdx.x * blockDim.x + threadIdx.x; i < n4; i += stride) {
      const float4 v = s[i];
      uint2 o;
      o.x = pack2(v.x, v.y);
      o.y = pack2(v.z, v.w);
      d[i] = o;
    }
  }
}

// ---------------- bf16 MFMA GEMM: C[M][N] = A[M][K] @ W[N][K]^T ----------------
// 64x64 tile, 4 waves (2x2), each wave 2x2 mfma_f32_16x16x32_bf16 fragments, BK=32.
// LDS layout per tile: 4 subtiles (16 rows x 32 k) stored as [kh(4)][row(16)][8 bf16]
// => fragment ds_read_b128 of lane l hits subtile byte l*16 (contiguous 1KB, conflict-free)
// and global_load_lds dest offset tid*16 is linear (wave-uniform base + lane*16).
__device__ __forceinline__ void gload_lds16(const unsigned short* g, unsigned short* l) {
  __builtin_amdgcn_global_load_lds(
      (const __attribute__((address_space(1))) void*)g,
      (__attribute__((address_space(3))) void*)l, 16, 0, 0);
}

__device__ __forceinline__ void gemm_mfma_body(
    const unsigned short* __restrict__ A, const unsigned short* __restrict__ W,
    float* __restrict__ C, int N, int K, int bm, int bn, int tid)
{
  __shared__ unsigned short As[2048];
  __shared__ unsigned short Bs[2048];
  const int lane = tid & 63;
  const int wave = tid >> 6;
  const int wr = wave >> 1, wc = wave & 1;

  // staging source for this thread (matches linear LDS slot tid*16B)
  const int sub = tid >> 6;          // subtile = wave
  const int kh  = (tid >> 4) & 3;    // k-chunk of 8 within BK=32
  const int row = tid & 15;
  const unsigned short* aSrc = A + (size_t)(bm + sub * 16 + row) * K + kh * 8;
  const unsigned short* bSrc = W + (size_t)(bn + sub * 16 + row) * K + kh * 8;
  unsigned short* ldsA = As + wave * 512;   // wave-uniform base
  unsigned short* ldsB = Bs + wave * 512;

  f32x4 acc[2][2];
#pragma unroll
  for (int m = 0; m < 2; ++m)
#pragma unroll
    for (int n = 0; n < 2; ++n) acc[m][n] = (f32x4){0.f, 0.f, 0.f, 0.f};

  for (int k0 = 0; k0 < K; k0 += 32) {
    gload_lds16(aSrc + k0, ldsA);
    gload_lds16(bSrc + k0, ldsB);
    __syncthreads();   // compiler drains vmcnt before s_barrier
    const bf16x8 a0 = *(const bf16x8*)(As + (wr * 2 + 0) * 512 + lane * 8);
    const bf16x8 a1 = *(const bf16x8*)(As + (wr * 2 + 1) * 512 + lane * 8);
    const bf16x8 b0 = *(const bf16x8*)(Bs + (wc * 2 + 0) * 512 + lane * 8);
    const bf16x8 b1 = *(const bf16x8*)(Bs + (wc * 2 + 1) * 512 + lane * 8);
    acc[0][0] = __builtin_amdgcn_mfma_f32_16x16x32_bf16(a0, b0, acc[0][0], 0, 0, 0);
    acc[0][1] = __builtin_amdgcn_mfma_f32_16x16x32_bf16(a0, b1, acc[0][1], 0, 0, 0);
    acc[1][0] = __builtin_amdgcn_mfma_f32_16x16x32_bf16(a1, b0, acc[1][0], 0, 0, 0);
    acc[1][1] = __builtin_amdgcn_mfma_f32_16x16x32_bf16(a1, b1, acc[1][1], 0, 0, 0);
    __syncthreads();
  }

  // C/D layout: col = lane&15, row = (lane>>4)*4 + reg  [m89 verified]
  const int cr = (lane >> 4) * 4;
  const int cc = lane & 15;
#pragma unroll
  for (int m = 0; m < 2; ++m)
#pragma unroll
    for (int n = 0; n < 2; ++n) {
      float* cp = C + (size_t)(bm + wr * 32 + m * 16 + cr) * N + (bn + wc * 32 + n * 16 + cc);
#pragma unroll
      for (int r = 0; r < 4; ++r) cp[(size_t)r * N] = acc[m][n][r];
    }
}

__global__ __launch_bounds__(256) void gemm_bf16(
    const unsigned short* __restrict__ A, const unsigned short* __restrict__ W,
    float* __restrict__ C, int N, int K)
{
  gemm_mfma_body(A, W, C, N, K, blockIdx.y * 64, blockIdx.x * 64, threadIdx.x);
}

struct W6 { const unsigned short* w[6]; };

__global__ __launch_bounds__(256) void gemm_bf16_kv6(
    const unsigned short* __restrict__ A, W6 p6, float* __restrict__ Cbase)
{
  gemm_mfma_body(A, p6.w[blockIdx.z], Cbase + (size_t)blockIdx.z * (SLEN * 256),
                 256, 1024, blockIdx.y * 64, blockIdx.x * 64, threadIdx.x);
}

// ---------------- RoPE (in place, pos = row index s) ----------------
__global__ void rope_q_kernel(float* __restrict__ buf)  // [S][16*64]
{
  const int s = blockIdx.x;
  const int t = threadIdx.x;          // 512 = 16 chunks * 32
  const int c = t >> 5, d = t & 31;
  float* p = buf + (size_t)s * 1024 + c * 64;
  const float inv = powf(10000.f, -(float)d * (1.f / 32.f));
  float sn, cs;
  sincosf((float)s * inv, &sn, &cs);
  const float x1 = p[d], x2 = p[d + 32];
  p[d]      = x1 * cs - x2 * sn;
  p[d + 32] = x1 * sn + x2 * cs;
}

__global__ void rope_k_kernel(float* __restrict__ kvbase) // ksel/kwin/kcmp via blockIdx.y
{
  const int s = blockIdx.x;
  const int which = blockIdx.y;       // 0->ksel, 1->kwin, 2->kcmp (offsets 0,2,4)
  const int t = threadIdx.x;          // 128 = 4 chunks * 32
  const int c = t >> 5, d = t & 31;
  float* p = kvbase + (size_t)which * 2 * (SLEN * 256) + (size_t)s * 256 + c * 64;
  const float inv = powf(10000.f, -(float)d * (1.f / 32.f));
  float sn, cs;
  sincosf((float)s * inv, &sn, &cs);
  const float x1 = p[d], x2 = p[d + 32];
  p[d]      = x1 * cs - x2 * sn;
  p[d + 32] = x1 * sn + x2 * cs;
}

// ---------------- cmp pooling: mean over 32-token windows ----------------
__global__ __launch_bounds__(64) void pool_kernel(
    const float* __restrict__ k_cmp, const float* __restrict__ v_cmp,
    float* __restrict__ Kc, float* __restrict__ Vc)
{
  const int c = blockIdx.x;   // 0..62
  const int g = blockIdx.y;   // 0..3
  const int d = threadIdx.x;  // 0..63
  float ak = 0.f, av = 0.f;
  for (int j = 0; j < 32; ++j) {
    const size_t off = (size_t)(c * 16 + j) * 256 + g * 64 + d;
    ak += k_cmp[off];
    av += v_cmp[off];
  }
  Kc[(size_t)(g * SCMP + c) * 64 + d] = ak * (1.f / 32.f);
  Vc[(size_t)(g * SCMP + c) * 64 + d] = av * (1.f / 32.f);
}

// ---------------- gating MLP ----------------
__global__ __launch_bounds__(64) void gate_kernel(
    const float* __restrict__ q, const float* __restrict__ g1w, const float* __restrict__ g1b,
    const float* __restrict__ g2w, const float* __restrict__ g2b, float* __restrict__ gates)
{
  const int s = blockIdx.x, g = blockIdx.y;
  const int t = threadIdx.x;
  __shared__ float qg[64], h1[32];
  const float* qb = q + (size_t)(s * 16 + g * 4) * 64;
  qg[t] = (qb[t] + qb[64 + t] + qb[128 + t] + qb[192 + t]) * 0.25f;
  __syncthreads();
  if (t < 32) {
    float a = g1b[t];
    for (int d = 0; d < 64; ++d) a += qg[d] * g1w[t * 64 + d];
    h1[t] = a / (1.f + expf(-a));   // silu
  }
  __syncthreads();
  if (t == 0) {
    float gl[3];
    for (int r = 0; r < 3; ++r) {
      float a = g2b[r];
      for (int j = 0; j < 32; ++j) a += h1[j] * g2w[r * 32 + j];
      gl[r] = a;  // TAU = 1
    }
    const float m1 = fmaxf(gl[0], fmaxf(gl[1], gl[2]));
    const float e0 = expf(gl[0] - m1), e1 = expf(gl[1] - m1), e2 = expf(gl[2] - m1);
    const float inv = 1.f / (e0 + e1 + e2);
    float p0 = e0 * inv, p1 = e1 * inv, p2 = e2 * inv;
    int am = 0; float best = gl[0];
    if (gl[1] > best) { best = gl[1]; am = 1; }
    if (gl[2] > best) { best = gl[2]; am = 2; }
    float second = -INFINITY;
    for (int r = 0; r < 3; ++r) if (r != am) second = fmaxf(second, gl[r]);
    if (best - second > 50.f) { p0 = (am == 0) ? 1.f : 0.f; p1 = (am == 1) ? 1.f : 0.f; p2 = (am == 2) ? 1.f : 0.f; }
    float* o = gates + (size_t)(s * 4 + g) * 3;
    o[0] = p0; o[1] = p1; o[2] = p2;
  }
}

// ---------------- fused NSA attention: one block per (s, g), wave = head ----------------
__global__ __launch_bounds__(256) void attn_kernel(
    const float* __restrict__ q,
    const float* __restrict__ k_sel, const float* __restrict__ v_sel,
    const float* __restrict__ k_win, const float* __restrict__ v_win,
    const float* __restrict__ Kc,    const float* __restrict__ Vc,
    const float* __restrict__ gates, float* __restrict__ O)
{
  const int s = blockIdx.x;
  const int g = blockIdx.y;
  const int tid = threadIdx.x;
  const int wave = tid >> 6;     // head within group
  const int lane = tid & 63;

  __shared__ float q_s[4][64];
  __shared__ float kt[64][65];       // +1 pad: per-lane row dot = 2-way bank (free)
  __shared__ float pc[4][64];
  __shared__ float p_lds[4][8][64];  // wave-private by head
  __shared__ float ps4[4][16];
  __shared__ float lg[16];
  __shared__ int   selblk[8];
  __shared__ int   nsel_s;

  q_s[wave][lane] = q[(size_t)(s * 16 + g * 4 + wave) * 64 + lane];
  for (int i = tid; i < SCMP * 64; i += 256) {
    const int r = i >> 6, c = i & 63;
    kt[r][c] = Kc[(size_t)(g * SCMP + r) * 64 + c];
  }
  __syncthreads();

  // ---- cmp branch: lane = compressed index c ----
  const int nv = (s >= 31) ? min(SCMP, ((s - 31) >> 4) + 1) : 0;
  float scc = -INFINITY;
  if (lane < nv) {
    float a = 0.f;
    for (int d = 0; d < 64; ++d) a += q_s[wave][d] * kt[lane][d];
    scc = a * SCALEF;
  }
  float mc = scc;
#pragma unroll
  for (int o = 32; o; o >>= 1) mc = fmaxf(mc, __shfl_xor(mc, o));
  const float pcv = (lane < nv) ? expf(scc - mc) : 0.f;
  float sumc = pcv;
#pragma unroll
  for (int o = 32; o; o >>= 1) sumc += __shfl_xor(sumc, o);
  pc[wave][lane] = (nv > 0) ? (pcv / sumc) : 0.f;
  __syncthreads();

  // O_cmp: lane = d
  float o_cmp = 0.f;
  for (int c = 0; c < nv; ++c)
    o_cmp += pc[wave][c] * Vc[(size_t)(g * SCMP + c) * 64 + lane];

  // per-head partial p_slc (M_MAP applied inline)
  if (lane < 16) {
    float a = 0.f;
    for (int c = 0; c < nv; ++c) {
      const int lo_ = max(c * 16, lane * 64);
      const int hi_ = min(c * 16 + 32, lane * 64 + 64);
      if (hi_ > lo_) a += pc[wave][c] * (float)(hi_ - lo_) * (1.f / 32.f);
    }
    ps4[wave][lane] = a;
  }
  __syncthreads();

  // selection logits (wave 0)
  if (wave == 0 && lane < 16) {
    const float psl = ps4[0][lane] + ps4[1][lane] + ps4[2][lane] + ps4[3][lane];
    const bool causal = (lane << 6) <= s;
    const bool forced = (lane == 0) || (lane == (s >> 6));
    lg[lane] = causal ? (psl + (forced ? 1e6f : 0.f)) : -1e9f;
  }
  __syncthreads();

  // top-8 set, top_k tie-break = (value desc, index asc)
  if (wave == 0) {
    bool sel = false;
    if (lane < 16) {
      const float my = lg[lane];
      int rank = 0;
      for (int m2 = 0; m2 < 16; ++m2) {
        const float v = lg[m2];
        if (v > my || (v == my && m2 < lane)) ++rank;
      }
      sel = (rank < NSELK) && ((lane << 6) <= s);  // non-causal picks are fully masked anyway
    }
    const unsigned long long msk = __ballot(sel);
    if (sel) selblk[__popcll(msk & ((1ull << lane) - 1ull))] = lane;
    if (lane == 0) nsel_s = (int)__popcll(msk);
  }
  __syncthreads();
  const int nsel = nsel_s;   // >= 1 (block 0 forced+causal)

  // ---- selected-blocks branch ----
  float sc8[8];
#pragma unroll
  for (int j = 0; j < 8; ++j) sc8[j] = -INFINITY;
#pragma unroll
  for (int j = 0; j < 8; ++j) {
    if (j < nsel) {                 // uniform across block
      const int base = selblk[j] << 6;
      __syncthreads();              // previous kt readers done
      for (int i = tid; i < 1024; i += 256) {
        const int r = i >> 4, c4 = (i & 15) << 2;
        const float4 kv4 = *reinterpret_cast<const float4*>(
            &k_sel[(size_t)(base + r) * 256 + g * 64 + c4]);
        kt[r][c4 + 0] = kv4.x; kt[r][c4 + 1] = kv4.y;
        kt[r][c4 + 2] = kv4.z; kt[r][c4 + 3] = kv4.w;
      }
      __syncthreads();
      if (base + lane <= s) {
        float a = 0.f;
        for (int d = 0; d < 64; ++d) a += q_s[wave][d] * kt[lane][d];
        sc8[j] = a * SCALEF;
      }
    }
  }
  float mx = -INFINITY;
#pragma unroll
  for (int j = 0; j < 8; ++j) mx = fmaxf(mx, sc8[j]);
#pragma unroll
  for (int o = 32; o; o >>= 1) mx = fmaxf(mx, __shfl_xor(mx, o));
  float dsel = 0.f;
#pragma unroll
  for (int j = 0; j < 8; ++j) {
    const float p = expf(sc8[j] - mx);  // exp(-inf)=0 for masked/unused
    p_lds[wave][j][lane] = p;
    dsel += p;
  }
#pragma unroll
  for (int o = 32; o; o >>= 1) dsel += __shfl_xor(dsel, o);
  __syncthreads();

  float o_sel = 0.f;
#pragma unroll
  for (int j = 0; j < 8; ++j) {
    if (j < nsel) {
      const int base = selblk[j] << 6;
      const int lim = min(63, s - base);
      for (int l = 0; l <= lim; ++l)
        o_sel += p_lds[wave][j][l] * v_sel[(size_t)(base + l) * 256 + g * 64 + lane];
    }
  }
  o_sel /= dsel;

  // ---- sliding-window branch ----
  const int lo = (s >= WWIN) ? (s - WWIN + 1) : 0;
  const int nch = ((s - lo + 1) + 63) >> 6;
#pragma unroll
  for (int j = 0; j < 8; ++j) sc8[j] = -INFINITY;
#pragma unroll
  for (int j = 0; j < 8; ++j) {
    if (j < nch) {                  // uniform
      const int base = lo + (j << 6);
      __syncthreads();
      for (int i = tid; i < 1024; i += 256) {
        const int r = i >> 4, c4 = (i & 15) << 2;
        const float4 kv4 = *reinterpret_cast<const float4*>(
            &k_win[(size_t)(base + r) * 256 + g * 64 + c4]);
        kt[r][c4 + 0] = kv4.x; kt[r][c4 + 1] = kv4.y;
        kt[r][c4 + 2] = kv4.z; kt[r][c4 + 3] = kv4.w;
      }
      __syncthreads();
      if (base + lane <= s) {
        float a = 0.f;
        for (int d = 0; d < 64; ++d) a += q_s[wave][d] * kt[lane][d];
        sc8[j] = a * SCALEF;
      }
    }
  }
  float mw = -INFINITY;
#pragma unroll
  for (int j = 0; j < 8; ++j) mw = fmaxf(mw, sc8[j]);
#pragma unroll
  for (int o = 32; o; o >>= 1) mw = fmaxf(mw, __shfl_xor(mw, o));
  float dwin = 0.f;
#pragma unroll
  for (int j = 0; j < 8; ++j) {
    const float p = expf(sc8[j] - mw);
    p_lds[wave][j][lane] = p;
    dwin += p;
  }
#pragma unroll
  for (int o = 32; o; o >>= 1) dwin += __shfl_xor(dwin, o);
  __syncthreads();

  float o_win = 0.f;
#pragma unroll
  for (int j = 0; j < 8; ++j) {
    if (j < nch) {
      const int base = lo + (j << 6);
      const int lim = min(63, s - base);
      for (int l = 0; l <= lim; ++l)
        o_win += p_lds[wave][j][l] * v_win[(size_t)(base + l) * 256 + g * 64 + lane];
    }
  }
  o_win /= dwin;

  // ---- gate combine, write O[s][g*4+wave][lane] ----
  const float* pg = gates + (size_t)(s * 4 + g) * 3;
  O[(size_t)(s * 16 + g * 4 + wave) * 64 + lane] =
      pg[0] * o_cmp + pg[1] * o_sel + pg[2] * o_win;
}

// ---------------- launch ----------------
extern "C" void kernel_launch(void* const* d_in, const int* in_sizes, int n_in,
                              void* d_out, int out_size, void* d_ws, size_t ws_size,
                              hipStream_t stream) {
  const float* x      = (const float*)d_in[0];
  const float* wq     = (const float*)d_in[1];
  const float* wk_sel = (const float*)d_in[2];
  const float* wv_sel = (const float*)d_in[3];
  const float* wk_win = (const float*)d_in[4];
  const float* wv_win = (const float*)d_in[5];
  const float* wk_cmp = (const float*)d_in[6];
  const float* wv_cmp = (const float*)d_in[7];
  const float* w_out  = (const float*)d_in[8];
  const float* g1w    = (const float*)d_in[9];
  const float* g1b    = (const float*)d_in[10];
  const float* g2w    = (const float*)d_in[11];
  const float* g2b    = (const float*)d_in[12];

  float* ws = (float*)d_ws;
  // f32 region: 3,714,560 floats (~14.9 MB)
  float* q     = ws;                       // 1048576
  float* kv    = q + 1048576;              // 6 * 262144
  float* ksel  = kv;
  float* vsel  = kv + 1 * 262144;
  float* kwin  = kv + 2 * 262144;
  float* vwin  = kv + 3 * 262144;
  float* kcmp  = kv + 4 * 262144;
  float* vcmp  = kv + 5 * 262144;
  float* Kc    = kv + 6 * 262144;          // 16128
  float* Vc    = Kc + 16128;               // 16128
  float* gts   = Vc + 16128;               // 12288
  float* Obuf  = gts + 12288;              // 1048576
  // bf16 region (~9 MB): xb reused as Obuf-bf16 after attn
  unsigned short* xb     = (unsigned short*)(Obuf + 1048576);  // 1048576
  unsigned short* wqb    = xb + 1048576;                       // 1048576
  unsigned short* kvwb   = wqb + 1048576;                      // 6*262144
  unsigned short* w_outb = kvwb + 6 * 262144;                  // 1048576

  // convert inputs to bf16
  ConvJobs j1 = {};
  j1.cnt = 9;
  j1.src[0] = x;      j1.dst[0] = (unsigned*)xb;               j1.n4[0] = 262144;
  j1.src[1] = wq;     j1.dst[1] = (unsigned*)wqb;              j1.n4[1] = 262144;
  j1.src[2] = wk_sel; j1.dst[2] = (unsigned*)(kvwb + 0*262144); j1.n4[2] = 65536;
  j1.src[3] = wv_sel; j1.dst[3] = (unsigned*)(kvwb + 1*262144); j1.n4[3] = 65536;
  j1.src[4] = wk_win; j1.dst[4] = (unsigned*)(kvwb + 2*262144); j1.n4[4] = 65536;
  j1.src[5] = wv_win; j1.dst[5] = (unsigned*)(kvwb + 3*262144); j1.n4[5] = 65536;
  j1.src[6] = wk_cmp; j1.dst[6] = (unsigned*)(kvwb + 4*262144); j1.n4[6] = 65536;
  j1.src[7] = wv_cmp; j1.dst[7] = (unsigned*)(kvwb + 5*262144); j1.n4[7] = 65536;
  j1.src[8] = w_out;  j1.dst[8] = (unsigned*)w_outb;           j1.n4[8] = 262144;
  conv_f32_bf16<<<1024, 256, 0, stream>>>(j1);

  // projections (bf16 MFMA)
  gemm_bf16<<<dim3(16, 16), 256, 0, stream>>>(xb, wqb, q, 1024, 1024);
  W6 p6 = {{ kvwb + 0*262144, kvwb + 1*262144, kvwb + 2*262144,
             kvwb + 3*262144, kvwb + 4*262144, kvwb + 5*262144 }};
  gemm_bf16_kv6<<<dim3(4, 16, 6), 256, 0, stream>>>(xb, p6, kv);

  // rope
  rope_q_kernel<<<1024, 512, 0, stream>>>(q);
  rope_k_kernel<<<dim3(1024, 3), 128, 0, stream>>>(kv);

  // compressed pooling
  pool_kernel<<<dim3(63, 4), 64, 0, stream>>>(kcmp, vcmp, Kc, Vc);

  // gates (uses roped q)
  gate_kernel<<<dim3(1024, 4), 64, 0, stream>>>(q, g1w, g1b, g2w, g2b, gts);

  // fused NSA attention
  attn_kernel<<<dim3(1024, 4), 256, 0, stream>>>(q, ksel, vsel, kwin, vwin, Kc, Vc, gts, Obuf);

  // output projection: convert Obuf -> bf16 (reuse xb), then MFMA GEMM
  ConvJobs j2 = {};
  j2.cnt = 1;
  j2.src[0] = Obuf; j2.dst[0] = (unsigned*)xb; j2.n4[0] = 262144;
  conv_f32_bf16<<<1024, 256, 0, stream>>>(j2);
  gemm_bf16<<<dim3(16, 16), 256, 0, stream>>>(xb, w_outb, (float*)d_out, 1024, 1024);
}

// Round 3
// 173.740 us; speedup vs baseline: 3.1818x; 1.8871x over previous
//
#include <hip/hip_runtime.h>
#include <math.h>

// ---------------- problem constants ----------------
#define SLEN   1024
#define NGRP   4
#define NHEAD  16
#define HPGRP  4
#define DKV    64
#define SCMP   63     // (1024-32)/16+1
#define NBLK   16
#define NSELK  8
#define WWIN   512
#define SCALEF 0.125f // 1/sqrt(64)
#define QBLK   32

typedef __attribute__((ext_vector_type(4))) float f32x4;
typedef __attribute__((ext_vector_type(8))) short bf16x8;

// ---------------- f32 -> bf16 (RNE) helpers ----------------
__device__ __forceinline__ unsigned short f2bf(float f) {
  unsigned u = __float_as_uint(f);
  u += 0x7FFFu + ((u >> 16) & 1u);
  return (unsigned short)(u >> 16);
}
__device__ __forceinline__ unsigned pack2(float a, float b) {
  return (unsigned)f2bf(a) | ((unsigned)f2bf(b) << 16);
}
__device__ __forceinline__ bf16x8 pack8(float4 a, float4 b) {
  union { bf16x8 v; unsigned u[4]; } u;
  u.u[0] = pack2(a.x, a.y); u.u[1] = pack2(a.z, a.w);
  u.u[2] = pack2(b.x, b.y); u.u[3] = pack2(b.z, b.w);
  return u.v;
}

struct ConvJobs {
  const float* src[9];
  unsigned* dst[9];
  int n4[9];
  int cnt;
};

__global__ __launch_bounds__(256) void conv_f32_bf16(ConvJobs jb) {
  const int stride = gridDim.x * blockDim.x;
  for (int t = 0; t < jb.cnt; ++t) {
    const float4* s = (const float4*)jb.src[t];
    uint2* d = (uint2*)jb.dst[t];
    const int n4 = jb.n4[t];
    for (int i = blockIdx.x * blockDim.x + threadIdx.x; i < n4; i += stride) {
      const float4 v = s[i];
      uint2 o;
      o.x = pack2(v.x, v.y);
      o.y = pack2(v.z, v.w);
      d[i] = o;
    }
  }
}

// ---------------- async global->LDS 16B ----------------
__device__ __forceinline__ void gload_lds16(const unsigned short* g, unsigned short* l) {
  __builtin_amdgcn_global_load_lds(
      (const __attribute__((address_space(1))) void*)g,
      (__attribute__((address_space(3))) void*)l, 16, 0, 0);
}

// ---------------- bf16 MFMA GEMM: C[M][N] = A[M][K] @ W[N][K]^T ----------------
__device__ __forceinline__ void gemm_mfma_body(
    const unsigned short* __restrict__ A, const unsigned short* __restrict__ W,
    float* __restrict__ C, int N, int K, int bm, int bn, int tid)
{
  __shared__ unsigned short As[2048];
  __shared__ unsigned short Bs[2048];
  const int lane = tid & 63;
  const int wave = tid >> 6;
  const int wr = wave >> 1, wc = wave & 1;

  const int sub = tid >> 6;
  const int kh  = (tid >> 4) & 3;
  const int row = tid & 15;
  const unsigned short* aSrc = A + (size_t)(bm + sub * 16 + row) * K + kh * 8;
  const unsigned short* bSrc = W + (size_t)(bn + sub * 16 + row) * K + kh * 8;
  unsigned short* ldsA = As + wave * 512;
  unsigned short* ldsB = Bs + wave * 512;

  f32x4 acc[2][2];
#pragma unroll
  for (int m = 0; m < 2; ++m)
#pragma unroll
    for (int n = 0; n < 2; ++n) acc[m][n] = (f32x4){0.f, 0.f, 0.f, 0.f};

  for (int k0 = 0; k0 < K; k0 += 32) {
    gload_lds16(aSrc + k0, ldsA);
    gload_lds16(bSrc + k0, ldsB);
    __syncthreads();
    const bf16x8 a0 = *(const bf16x8*)(As + (wr * 2 + 0) * 512 + lane * 8);
    const bf16x8 a1 = *(const bf16x8*)(As + (wr * 2 + 1) * 512 + lane * 8);
    const bf16x8 b0 = *(const bf16x8*)(Bs + (wc * 2 + 0) * 512 + lane * 8);
    const bf16x8 b1 = *(const bf16x8*)(Bs + (wc * 2 + 1) * 512 + lane * 8);
    acc[0][0] = __builtin_amdgcn_mfma_f32_16x16x32_bf16(a0, b0, acc[0][0], 0, 0, 0);
    acc[0][1] = __builtin_amdgcn_mfma_f32_16x16x32_bf16(a0, b1, acc[0][1], 0, 0, 0);
    acc[1][0] = __builtin_amdgcn_mfma_f32_16x16x32_bf16(a1, b0, acc[1][0], 0, 0, 0);
    acc[1][1] = __builtin_amdgcn_mfma_f32_16x16x32_bf16(a1, b1, acc[1][1], 0, 0, 0);
    __syncthreads();
  }

  const int cr = (lane >> 4) * 4;
  const int cc = lane & 15;
#pragma unroll
  for (int m = 0; m < 2; ++m)
#pragma unroll
    for (int n = 0; n < 2; ++n) {
      float* cp = C + (size_t)(bm + wr * 32 + m * 16 + cr) * N + (bn + wc * 32 + n * 16 + cc);
#pragma unroll
      for (int r = 0; r < 4; ++r) cp[(size_t)r * N] = acc[m][n][r];
    }
}

__global__ __launch_bounds__(256) void gemm_bf16(
    const unsigned short* __restrict__ A, const unsigned short* __restrict__ W,
    float* __restrict__ C, int N, int K)
{
  gemm_mfma_body(A, W, C, N, K, blockIdx.y * 64, blockIdx.x * 64, threadIdx.x);
}

struct W6 { const unsigned short* w[6]; };

__global__ __launch_bounds__(256) void gemm_bf16_kv6(
    const unsigned short* __restrict__ A, W6 p6, float* __restrict__ Cbase)
{
  gemm_mfma_body(A, p6.w[blockIdx.z], Cbase + (size_t)blockIdx.z * (SLEN * 256),
                 256, 1024, blockIdx.y * 64, blockIdx.x * 64, threadIdx.x);
}

// ---------------- RoPE ----------------
__global__ void rope_q_kernel(float* __restrict__ buf)
{
  const int s = blockIdx.x;
  const int t = threadIdx.x;
  const int c = t >> 5, d = t & 31;
  float* p = buf + (size_t)s * 1024 + c * 64;
  const float inv = powf(10000.f, -(float)d * (1.f / 32.f));
  float sn, cs;
  sincosf((float)s * inv, &sn, &cs);
  const float x1 = p[d], x2 = p[d + 32];
  p[d]      = x1 * cs - x2 * sn;
  p[d + 32] = x1 * sn + x2 * cs;
}

__global__ void rope_k_kernel(float* __restrict__ kvbase)
{
  const int s = blockIdx.x;
  const int which = blockIdx.y;
  const int t = threadIdx.x;
  const int c = t >> 5, d = t & 31;
  float* p = kvbase + (size_t)which * 2 * (SLEN * 256) + (size_t)s * 256 + c * 64;
  const float inv = powf(10000.f, -(float)d * (1.f / 32.f));
  float sn, cs;
  sincosf((float)s * inv, &sn, &cs);
  const float x1 = p[d], x2 = p[d + 32];
  p[d]      = x1 * cs - x2 * sn;
  p[d + 32] = x1 * sn + x2 * cs;
}

// ---------------- cmp pooling -> padded bf16 (Kc row-major, Vc transposed) ----------------
__global__ __launch_bounds__(64) void pool_kernel(
    const float* __restrict__ k_cmp, const float* __restrict__ v_cmp,
    unsigned short* __restrict__ KcB, unsigned short* __restrict__ VcTB)
{
  const int c = blockIdx.x;   // 0..63 (63 = zero pad)
  const int g = blockIdx.y;
  const int d = threadIdx.x;
  float ak = 0.f, av = 0.f;
  if (c < SCMP) {
    for (int j = 0; j < 32; ++j) {
      const size_t off = (size_t)(c * 16 + j) * 256 + g * 64 + d;
      ak += k_cmp[off];
      av += v_cmp[off];
    }
    ak *= (1.f / 32.f); av *= (1.f / 32.f);
  }
  KcB[(size_t)(g * 64 + c) * 64 + d] = f2bf(ak);
  VcTB[(size_t)(g * 64 + d) * 64 + c] = f2bf(av);
}

// ---------------- V transpose: [1024][256] f32 -> [256][1024] bf16 ----------------
__global__ __launch_bounds__(256) void transpose_v(
    const float* __restrict__ v0, const float* __restrict__ v1,
    unsigned short* __restrict__ t0, unsigned short* __restrict__ t1)
{
  const float* src = blockIdx.z ? v1 : v0;
  unsigned short* dst = blockIdx.z ? t1 : t0;
  __shared__ float tile[32][33];
  const int tr = blockIdx.x * 32, tc = blockIdx.y * 32;
  const int r = threadIdx.x >> 5, c = threadIdx.x & 31;
#pragma unroll
  for (int i = 0; i < 4; ++i)
    tile[r + i * 8][c] = src[(size_t)(tr + r + i * 8) * 256 + tc + c];
  __syncthreads();
#pragma unroll
  for (int i = 0; i < 4; ++i)
    dst[(size_t)(tc + r + i * 8) * 1024 + tr + c] = f2bf(tile[c][r + i * 8]);
}

// ---------------- gating MLP ----------------
__global__ __launch_bounds__(64) void gate_kernel(
    const float* __restrict__ q, const float* __restrict__ g1w, const float* __restrict__ g1b,
    const float* __restrict__ g2w, const float* __restrict__ g2b, float* __restrict__ gates)
{
  const int s = blockIdx.x, g = blockIdx.y;
  const int t = threadIdx.x;
  __shared__ float qg[64], h1[32];
  const float* qb = q + (size_t)(s * 16 + g * 4) * 64;
  qg[t] = (qb[t] + qb[64 + t] + qb[128 + t] + qb[192 + t]) * 0.25f;
  __syncthreads();
  if (t < 32) {
    float a = g1b[t];
    for (int d = 0; d < 64; ++d) a += qg[d] * g1w[t * 64 + d];
    h1[t] = a / (1.f + expf(-a));
  }
  __syncthreads();
  if (t == 0) {
    float gl[3];
    for (int r = 0; r < 3; ++r) {
      float a = g2b[r];
      for (int j = 0; j < 32; ++j) a += h1[j] * g2w[r * 32 + j];
      gl[r] = a;
    }
    const float m1 = fmaxf(gl[0], fmaxf(gl[1], gl[2]));
    const float e0 = expf(gl[0] - m1), e1 = expf(gl[1] - m1), e2 = expf(gl[2] - m1);
    const float inv = 1.f / (e0 + e1 + e2);
    float p0 = e0 * inv, p1 = e1 * inv, p2 = e2 * inv;
    int am = 0; float best = gl[0];
    if (gl[1] > best) { best = gl[1]; am = 1; }
    if (gl[2] > best) { best = gl[2]; am = 2; }
    float second = -INFINITY;
    for (int r = 0; r < 3; ++r) if (r != am) second = fmaxf(second, gl[r]);
    if (best - second > 50.f) { p0 = (am == 0) ? 1.f : 0.f; p1 = (am == 1) ? 1.f : 0.f; p2 = (am == 2) ? 1.f : 0.f; }
    float* o = gates + (size_t)(s * 4 + g) * 3;
    o[0] = p0; o[1] = p1; o[2] = p2;
  }
}

// ---------------- MFMA NSA attention ----------------
// block = (qtile of 32 rows, group g); 8 waves = 4 heads x 2 row-halves; wave owns 16 q-rows.
// Per kv-tile (64 tokens): QK^T (A=Q,B=K) -> per-row online softmax in C-layout ->
// P via wave-private LDS (f32, stride 76) -> A-fragment -> PV (A=P,B=V).
// BR: 0=cmp, 1=sel (per-row 16-bit block mask), 2=win (sliding window).
template<int BR>
__device__ __forceinline__ void attn_tile(
    const unsigned short* ksrc, const unsigned short* vsrc,
    int b, int s0, int w, int l, int tid,
    bf16x8 aq0, bf16x8 aq1,
    float (&m)[4], float (&ls)[4], f32x4 (&Oa)[4],
    unsigned short* Klds, unsigned short* Vlds,
    float (*Pw)[76], float (*lcS)[16], const unsigned* selmaskS)
{
  __syncthreads();                       // prior tile's LDS reads complete
  gload_lds16(ksrc, Klds + tid * 8);
  gload_lds16(vsrc, Vlds + tid * 8);
  __syncthreads();                       // drains vmcnt: tiles ready

  const int kg = l >> 4, lr = l & 15;
  f32x4 sc[4];
#pragma unroll
  for (int f = 0; f < 4; ++f) {
    sc[f] = (f32x4){0.f, 0.f, 0.f, 0.f};
    sc[f] = __builtin_amdgcn_mfma_f32_16x16x32_bf16(
        aq0, *(const bf16x8*)(Klds + (f * 2 + 0) * 512 + l * 8), sc[f], 0, 0, 0);
    sc[f] = __builtin_amdgcn_mfma_f32_16x16x32_bf16(
        aq1, *(const bf16x8*)(Klds + (f * 2 + 1) * 512 + l * 8), sc[f], 0, 0, 0);
  }

  // mask + scale in C layout: row=(l>>4)*4+r, col=16f+lr
  float mnew[4], scale[4], ps[4];
#pragma unroll
  for (int r = 0; r < 4; ++r) {
    const int lrow = (w & 1) * 16 + kg * 4 + r;
    const int sr = s0 + lrow;
#pragma unroll
    for (int f = 0; f < 4; ++f) {
      const int tok = b * 64 + 16 * f + lr;
      bool ok;
      if (BR == 0)      ok = (tok < SCMP) && (tok * 16 + 31 <= sr);
      else if (BR == 1) ok = ((selmaskS[lrow] >> b) & 1u) && (tok <= sr);
      else              ok = (tok <= sr) && (tok > sr - WWIN);
      sc[f][r] = ok ? sc[f][r] * SCALEF : -1e30f;
    }
  }
  float tm[4];
#pragma unroll
  for (int r = 0; r < 4; ++r) {
    tm[r] = fmaxf(fmaxf(sc[0][r], sc[1][r]), fmaxf(sc[2][r], sc[3][r]));
    tm[r] = fmaxf(tm[r], __shfl_xor(tm[r], 1));
    tm[r] = fmaxf(tm[r], __shfl_xor(tm[r], 2));
    tm[r] = fmaxf(tm[r], __shfl_xor(tm[r], 4));
    tm[r] = fmaxf(tm[r], __shfl_xor(tm[r], 8));
    mnew[r] = fmaxf(m[r], tm[r]);
    scale[r] = __expf(m[r] - mnew[r]);   // both -1e30 -> exp(0)=1, harmless (O=0,l=0)
    ps[r] = 0.f;
  }
#pragma unroll
  for (int f = 0; f < 4; ++f)
#pragma unroll
    for (int r = 0; r < 4; ++r) {
      const float p = (sc[f][r] > -1e29f) ? __expf(sc[f][r] - mnew[r]) : 0.f;
      Pw[kg * 4 + r][16 * f + lr] = p;
      ps[r] += p;
    }
#pragma unroll
  for (int r = 0; r < 4; ++r) {
    ps[r] += __shfl_xor(ps[r], 1);
    ps[r] += __shfl_xor(ps[r], 2);
    ps[r] += __shfl_xor(ps[r], 4);
    ps[r] += __shfl_xor(ps[r], 8);
    ls[r] = ls[r] * scale[r] + ps[r];
    m[r] = mnew[r];
  }
  if (BR == 0 && lr == 0) {
#pragma unroll
    for (int r = 0; r < 4; ++r) lcS[w][kg * 4 + r] = ls[r];
  }
#pragma unroll
  for (int f = 0; f < 4; ++f) {
    Oa[f][0] *= scale[0]; Oa[f][1] *= scale[1];
    Oa[f][2] *= scale[2]; Oa[f][3] *= scale[3];
  }
  asm volatile("s_waitcnt lgkmcnt(0)" ::: "memory");  // wave's P writes visible to its reads
#pragma unroll
  for (int ks = 0; ks < 2; ++ks) {
    const float4 pa0 = *(const float4*)&Pw[lr][ks * 32 + kg * 8];
    const float4 pa1 = *(const float4*)&Pw[lr][ks * 32 + kg * 8 + 4];
    const bf16x8 pa = pack8(pa0, pa1);
#pragma unroll
    for (int f = 0; f < 4; ++f)
      Oa[f] = __builtin_amdgcn_mfma_f32_16x16x32_bf16(
          pa, *(const bf16x8*)(Vlds + (f * 2 + ks) * 512 + l * 8), Oa[f], 0, 0, 0);
  }
}

__global__ __launch_bounds__(512) void attn_mfma_kernel(
    const unsigned short* __restrict__ qb,     // [S][16][64] bf16
    const unsigned short* __restrict__ kselb,  // [S][256] bf16
    const unsigned short* __restrict__ vselT,  // [256][S] bf16
    const unsigned short* __restrict__ kwinb,
    const unsigned short* __restrict__ vwinT,
    const unsigned short* __restrict__ KcB,    // [g*64+c][64] bf16 (c=63 pad)
    const unsigned short* __restrict__ VcTB,   // [g*64+d][64] bf16
    const float* __restrict__ gates,           // [S][4][3]
    float* __restrict__ O)                     // [S][16][64] f32
{
  const int qt = blockIdx.x;
  const int g  = blockIdx.y;
  const int s0 = qt * QBLK;
  const int tid = threadIdx.x;
  const int w = tid >> 6, l = tid & 63;
  const int h = w >> 1;
  const int kg = l >> 4, lr = l & 15;

  __shared__ unsigned short Klds[4096];
  __shared__ unsigned short Vlds[4096];
  __shared__ float Plds[8][16][76];
  __shared__ float lgS[QBLK][16];
  __shared__ float lcS[8][16];
  __shared__ unsigned selmaskS[QBLK];
  __shared__ unsigned selunionS;

  if (tid < QBLK) selmaskS[tid] = 0u;

  const int sf = tid >> 7, sks = (tid >> 6) & 1, skh = (tid >> 4) & 3, stk = tid & 15;

  // Q A-fragments (row = lr, k-run = kg*8)
  const int sq = s0 + (w & 1) * 16 + lr;
  const unsigned short* qrow = qb + (size_t)(sq * 16 + g * 4 + h) * 64;
  const bf16x8 aq0 = *(const bf16x8*)(qrow + kg * 8);
  const bf16x8 aq1 = *(const bf16x8*)(qrow + 32 + kg * 8);

  // gates per C-layout row
  float gv[3][4];
#pragma unroll
  for (int r = 0; r < 4; ++r) {
    const int sr = s0 + (w & 1) * 16 + kg * 4 + r;
    const float* gp = gates + (size_t)(sr * 4 + g) * 3;
    gv[0][r] = gp[0]; gv[1][r] = gp[1]; gv[2][r] = gp[2];
  }

  f32x4 Ot[4];
#pragma unroll
  for (int f = 0; f < 4; ++f) Ot[f] = (f32x4){0.f, 0.f, 0.f, 0.f};

  float m[4], ls[4];
  f32x4 Oa[4];

#define ARESET() do { \
    _Pragma("unroll") for (int r = 0; r < 4; ++r) { m[r] = -1e30f; ls[r] = 0.f; } \
    _Pragma("unroll") for (int f = 0; f < 4; ++f) Oa[f] = (f32x4){0.f,0.f,0.f,0.f}; \
  } while (0)
#define AFINAL(bi) do { \
    _Pragma("unroll") for (int f = 0; f < 4; ++f) \
    _Pragma("unroll") for (int r = 0; r < 4; ++r) \
      Ot[f][r] += gv[bi][r] * ((ls[r] > 0.f) ? (Oa[f][r] / ls[r]) : 0.f); \
  } while (0)

  // ---- cmp branch ----
  ARESET();
  {
    const unsigned short* ksrc = KcB  + (size_t)(g * 64 + 16 * sf + stk) * 64 + sks * 32 + skh * 8;
    const unsigned short* vsrc = VcTB + (size_t)(g * 64 + 16 * sf + stk) * 64 + sks * 32 + skh * 8;
    attn_tile<0>(ksrc, vsrc, 0, s0, w, l, tid, aq0, aq1, m, ls, Oa,
                 Klds, Vlds, Plds[w], lcS, selmaskS);
  }
  AFINAL(0);
  __syncthreads();   // cmp P + lcS visible block-wide

  // ---- selection: p_slc (M_MAP inline), lg, top-8 ----
  {
    const int row = tid >> 4, mm = tid & 15;
    const int sr = s0 + row;
    float psl = 0.f;
#pragma unroll
    for (int hh = 0; hh < 4; ++hh) {
      const int wv = hh * 2 + (row >> 4);
      const int r16 = row & 15;
      const float lc = lcS[wv][r16];
      if (lc > 0.f) {
        const int cb = 4 * mm;
        float a = Plds[wv][r16][cb] + Plds[wv][r16][cb + 1] + Plds[wv][r16][cb + 2];
        if (cb >= 1)         a += 0.5f * Plds[wv][r16][cb - 1];
        if (cb + 3 < SCMP)   a += 0.5f * Plds[wv][r16][cb + 3];
        psl += a / lc;
      }
    }
    const bool causal = (mm << 6) <= sr;
    const bool forced = (mm == 0) || (mm == (sr >> 6));
    lgS[row][mm] = causal ? (psl + (forced ? 1e6f : 0.f)) : -1e9f;
  }
  __syncthreads();
  {
    const int row = tid >> 4, mm = tid & 15;
    const float my = lgS[row][mm];
    int rank = 0;
#pragma unroll
    for (int m2 = 0; m2 < 16; ++m2) {
      const float v = lgS[row][m2];
      if (v > my || (v == my && m2 < mm)) ++rank;
    }
    if (rank < NSELK) atomicOr(&selmaskS[row], 1u << mm);
  }
  __syncthreads();
  if (tid == 0) {
    unsigned u = 0;
    for (int r = 0; r < QBLK; ++r) u |= selmaskS[r];
    selunionS = u;
  }
  __syncthreads();
  const unsigned su = selunionS;
  const int bmax = (s0 + QBLK - 1) >> 6;

  // ---- sel branch: dense over union of selected blocks, per-row mask ----
  ARESET();
  for (int b = 0; b <= bmax; ++b) {
    if (!((su >> b) & 1u)) continue;
    const unsigned short* ksrc = kselb + (size_t)(b * 64 + 16 * sf + stk) * 256 + g * 64 + sks * 32 + skh * 8;
    const unsigned short* vsrc = vselT + (size_t)(g * 64 + 16 * sf + stk) * 1024 + b * 64 + sks * 32 + skh * 8;
    attn_tile<1>(ksrc, vsrc, b, s0, w, l, tid, aq0, aq1, m, ls, Oa,
                 Klds, Vlds, Plds[w], lcS, selmaskS);
  }
  AFINAL(1);

  // ---- win branch ----
  ARESET();
  const int blo = (s0 >= (WWIN - 1)) ? ((s0 - (WWIN - 1)) >> 6) : 0;
  for (int b = blo; b <= bmax; ++b) {
    const unsigned short* ksrc = kwinb + (size_t)(b * 64 + 16 * sf + stk) * 256 + g * 64 + sks * 32 + skh * 8;
    const unsigned short* vsrc = vwinT + (size_t)(g * 64 + 16 * sf + stk) * 1024 + b * 64 + sks * 32 + skh * 8;
    attn_tile<2>(ksrc, vsrc, b, s0, w, l, tid, aq0, aq1, m, ls, Oa,
                 Klds, Vlds, Plds[w], lcS, selmaskS);
  }
  AFINAL(2);

  // ---- write O ----
#pragma unroll
  for (int f = 0; f < 4; ++f)
#pragma unroll
    for (int r = 0; r < 4; ++r) {
      const int sr = s0 + (w & 1) * 16 + kg * 4 + r;
      O[(size_t)(sr * 16 + g * 4 + h) * 64 + 16 * f + lr] = Ot[f][r];
    }
#undef ARESET
#undef AFINAL
}

// ---------------- launch ----------------
extern "C" void kernel_launch(void* const* d_in, const int* in_sizes, int n_in,
                              void* d_out, int out_size, void* d_ws, size_t ws_size,
                              hipStream_t stream) {
  const float* x      = (const float*)d_in[0];
  const float* wq     = (const float*)d_in[1];
  const float* wk_sel = (const float*)d_in[2];
  const float* wv_sel = (const float*)d_in[3];
  const float* wk_win = (const float*)d_in[4];
  const float* wv_win = (const float*)d_in[5];
  const float* wk_cmp = (const float*)d_in[6];
  const float* wv_cmp = (const float*)d_in[7];
  const float* w_out  = (const float*)d_in[8];
  const float* g1w    = (const float*)d_in[9];
  const float* g1b    = (const float*)d_in[10];
  const float* g2w    = (const float*)d_in[11];
  const float* g2b    = (const float*)d_in[12];

  float* ws = (float*)d_ws;
  float* q     = ws;                         // 1,048,576 f32
  float* kv    = q + 1048576;                // 6 x 262,144 f32
  float* ksel  = kv;
  float* vsel  = kv + 1 * 262144;
  float* kwin  = kv + 2 * 262144;
  float* vwin  = kv + 3 * 262144;
  float* kcmp  = kv + 4 * 262144;
  float* vcmp  = kv + 5 * 262144;
  float* gts   = kv + 6 * 262144;            // 12,288 f32
  float* Obuf  = gts + 12288;                // 1,048,576 f32

  unsigned short* xb     = (unsigned short*)(Obuf + 1048576);
  unsigned short* wqb    = xb + 1048576;
  unsigned short* kvwb   = wqb + 1048576;    // 6 x 262,144
  unsigned short* w_outb = kvwb + 6 * 262144;
  unsigned short* q_b    = w_outb + 1048576; // 1,048,576
  unsigned short* kselb  = q_b + 1048576;    // 262,144
  unsigned short* kwinb  = kselb + 262144;
  unsigned short* vselT  = kwinb + 262144;   // 262,144 (transposed)
  unsigned short* vwinT  = vselT + 262144;
  unsigned short* KcB    = vwinT + 262144;   // 16,384
  unsigned short* VcTB   = KcB + 16384;      // 16,384

  // inputs -> bf16
  ConvJobs j1 = {};
  j1.cnt = 9;
  j1.src[0] = x;      j1.dst[0] = (unsigned*)xb;                j1.n4[0] = 262144;
  j1.src[1] = wq;     j1.dst[1] = (unsigned*)wqb;               j1.n4[1] = 262144;
  j1.src[2] = wk_sel; j1.dst[2] = (unsigned*)(kvwb + 0*262144); j1.n4[2] = 65536;
  j1.src[3] = wv_sel; j1.dst[3] = (unsigned*)(kvwb + 1*262144); j1.n4[3] = 65536;
  j1.src[4] = wk_win; j1.dst[4] = (unsigned*)(kvwb + 2*262144); j1.n4[4] = 65536;
  j1.src[5] = wv_win; j1.dst[5] = (unsigned*)(kvwb + 3*262144); j1.n4[5] = 65536;
  j1.src[6] = wk_cmp; j1.dst[6] = (unsigned*)(kvwb + 4*262144); j1.n4[6] = 65536;
  j1.src[7] = wv_cmp; j1.dst[7] = (unsigned*)(kvwb + 5*262144); j1.n4[7] = 65536;
  j1.src[8] = w_out;  j1.dst[8] = (unsigned*)w_outb;            j1.n4[8] = 262144;
  conv_f32_bf16<<<1024, 256, 0, stream>>>(j1);

  // projections
  gemm_bf16<<<dim3(16, 16), 256, 0, stream>>>(xb, wqb, q, 1024, 1024);
  W6 p6 = {{ kvwb + 0*262144, kvwb + 1*262144, kvwb + 2*262144,
             kvwb + 3*262144, kvwb + 4*262144, kvwb + 5*262144 }};
  gemm_bf16_kv6<<<dim3(4, 16, 6), 256, 0, stream>>>(xb, p6, kv);

  // rope
  rope_q_kernel<<<1024, 512, 0, stream>>>(q);
  rope_k_kernel<<<dim3(1024, 3), 128, 0, stream>>>(kv);

  // pooled cmp K/V -> bf16 (padded, V transposed)
  pool_kernel<<<dim3(64, 4), 64, 0, stream>>>(kcmp, vcmp, KcB, VcTB);

  // gates (f32 q)
  gate_kernel<<<dim3(1024, 4), 64, 0, stream>>>(q, g1w, g1b, g2w, g2b, gts);

  // q/k -> bf16
  ConvJobs j2 = {};
  j2.cnt = 3;
  j2.src[0] = q;    j2.dst[0] = (unsigned*)q_b;   j2.n4[0] = 262144;
  j2.src[1] = ksel; j2.dst[1] = (unsigned*)kselb; j2.n4[1] = 65536;
  j2.src[2] = kwin; j2.dst[2] = (unsigned*)kwinb; j2.n4[2] = 65536;
  conv_f32_bf16<<<1024, 256, 0, stream>>>(j2);

  // v -> transposed bf16
  transpose_v<<<dim3(32, 8, 2), 256, 0, stream>>>(vsel, vwin, vselT, vwinT);

  // fused MFMA NSA attention
  attn_mfma_kernel<<<dim3(32, 4), 512, 0, stream>>>(
      q_b, kselb, vselT, kwinb, vwinT, KcB, VcTB, gts, Obuf);

  // output projection
  ConvJobs j3 = {};
  j3.cnt = 1;
  j3.src[0] = Obuf; j3.dst[0] = (unsigned*)xb; j3.n4[0] = 262144;
  conv_f32_bf16<<<1024, 256, 0, stream>>>(j3);
  gemm_bf16<<<dim3(16, 16), 256, 0, stream>>>(xb, w_outb, (float*)d_out, 1024, 1024);
}

// Round 4
// 150.443 us; speedup vs baseline: 3.6745x; 1.1549x over previous
//
#include <hip/hip_runtime.h>
#include <math.h>

// ---------------- problem constants ----------------
#define SLEN   1024
#define NGRP   4
#define NHEAD  16
#define HPGRP  4
#define DKV    64
#define SCMP   63     // (1024-32)/16+1
#define NBLK   16
#define NSELK  8
#define WWIN   512
#define SCALEF 0.125f // 1/sqrt(64)
#define QBLK   32

typedef __attribute__((ext_vector_type(4))) float f32x4;
typedef __attribute__((ext_vector_type(8))) short bf16x8;

// ---------------- f32 -> bf16 (RNE) helpers ----------------
__device__ __forceinline__ unsigned short f2bf(float f) {
  unsigned u = __float_as_uint(f);
  u += 0x7FFFu + ((u >> 16) & 1u);
  return (unsigned short)(u >> 16);
}
__device__ __forceinline__ unsigned pack2(float a, float b) {
  return (unsigned)f2bf(a) | ((unsigned)f2bf(b) << 16);
}
__device__ __forceinline__ bf16x8 pack8(float4 a, float4 b) {
  union { bf16x8 v; unsigned u[4]; } u;
  u.u[0] = pack2(a.x, a.y); u.u[1] = pack2(a.z, a.w);
  u.u[2] = pack2(b.x, b.y); u.u[3] = pack2(b.z, b.w);
  return u.v;
}

struct ConvJobs {
  const float* src[9];
  unsigned* dst[9];
  int n4[9];
  int cnt;
};

__global__ __launch_bounds__(256) void conv_f32_bf16(ConvJobs jb) {
  const int stride = gridDim.x * blockDim.x;
  for (int t = 0; t < jb.cnt; ++t) {
    const float4* s = (const float4*)jb.src[t];
    uint2* d = (uint2*)jb.dst[t];
    const int n4 = jb.n4[t];
    for (int i = blockIdx.x * blockDim.x + threadIdx.x; i < n4; i += stride) {
      const float4 v = s[i];
      uint2 o;
      o.x = pack2(v.x, v.y);
      o.y = pack2(v.z, v.w);
      d[i] = o;
    }
  }
}

// sum two f32 buffers -> bf16 (gate-combined attention output)
__global__ __launch_bounds__(256) void conv_add_bf16(
    const float* __restrict__ a, const float* __restrict__ b, uint2* __restrict__ d)
{
  const int i = blockIdx.x * 256 + threadIdx.x;   // 262144 float4s, grid 1024
  const float4 va = ((const float4*)a)[i];
  const float4 vb = ((const float4*)b)[i];
  uint2 o;
  o.x = pack2(va.x + vb.x, va.y + vb.y);
  o.y = pack2(va.z + vb.z, va.w + vb.w);
  d[i] = o;
}

// ---------------- async global->LDS 16B ----------------
__device__ __forceinline__ void gload_lds16(const unsigned short* g, unsigned short* l) {
  __builtin_amdgcn_global_load_lds(
      (const __attribute__((address_space(1))) void*)g,
      (__attribute__((address_space(3))) void*)l, 16, 0, 0);
}

// ---------------- bf16 MFMA GEMM: C[M][N] = A[M][K] @ W[N][K]^T ----------------
// 64x64 tile, 4 waves (2x2), 2x2 fragments each, BK=32.
// 3-buffer LDS pipeline, 2 tiles in flight, counted vmcnt(2), 1 barrier/K-step.
__device__ __forceinline__ void gemm_mfma_body(
    const unsigned short* __restrict__ A, const unsigned short* __restrict__ W,
    float* __restrict__ C, int N, int K, int bm, int bn, int tid)
{
  __shared__ unsigned short As[3][2048];
  __shared__ unsigned short Bs[3][2048];
  const int lane = tid & 63;
  const int wave = tid >> 6;
  const int wr = wave >> 1, wc = wave & 1;

  const int sub = tid >> 6;
  const int kh  = (tid >> 4) & 3;
  const int row = tid & 15;
  const unsigned short* aSrc = A + (size_t)(bm + sub * 16 + row) * K + kh * 8;
  const unsigned short* bSrc = W + (size_t)(bn + sub * 16 + row) * K + kh * 8;
  const int slot = tid * 8;

  f32x4 acc[2][2];
#pragma unroll
  for (int m = 0; m < 2; ++m)
#pragma unroll
    for (int n = 0; n < 2; ++n) acc[m][n] = (f32x4){0.f, 0.f, 0.f, 0.f};

  const int NIT = K >> 5;
  // prologue: tiles 0 and 1 in flight
  gload_lds16(aSrc + 0,  &As[0][slot]);
  gload_lds16(bSrc + 0,  &Bs[0][slot]);
  gload_lds16(aSrc + 32, &As[1][slot]);
  gload_lds16(bSrc + 32, &Bs[1][slot]);

  for (int i = 0; i < NIT; ++i) {
    __builtin_amdgcn_sched_barrier(0);
    if (i + 1 < NIT) asm volatile("s_waitcnt vmcnt(2)" ::: "memory");
    else             asm volatile("s_waitcnt vmcnt(0)" ::: "memory");
    __builtin_amdgcn_s_barrier();
    __builtin_amdgcn_sched_barrier(0);
    if (i + 2 < NIT) {
      const int nb = (i + 2) % 3;
      gload_lds16(aSrc + (i + 2) * 32, &As[nb][slot]);
      gload_lds16(bSrc + (i + 2) * 32, &Bs[nb][slot]);
    }
    const int cur = i % 3;
    const bf16x8 a0 = *(const bf16x8*)(&As[cur][(wr * 2 + 0) * 512 + lane * 8]);
    const bf16x8 a1 = *(const bf16x8*)(&As[cur][(wr * 2 + 1) * 512 + lane * 8]);
    const bf16x8 b0 = *(const bf16x8*)(&Bs[cur][(wc * 2 + 0) * 512 + lane * 8]);
    const bf16x8 b1 = *(const bf16x8*)(&Bs[cur][(wc * 2 + 1) * 512 + lane * 8]);
    acc[0][0] = __builtin_amdgcn_mfma_f32_16x16x32_bf16(a0, b0, acc[0][0], 0, 0, 0);
    acc[0][1] = __builtin_amdgcn_mfma_f32_16x16x32_bf16(a0, b1, acc[0][1], 0, 0, 0);
    acc[1][0] = __builtin_amdgcn_mfma_f32_16x16x32_bf16(a1, b0, acc[1][0], 0, 0, 0);
    acc[1][1] = __builtin_amdgcn_mfma_f32_16x16x32_bf16(a1, b1, acc[1][1], 0, 0, 0);
  }

  const int cr = (lane >> 4) * 4;
  const int cc = lane & 15;
#pragma unroll
  for (int m = 0; m < 2; ++m)
#pragma unroll
    for (int n = 0; n < 2; ++n) {
      float* cp = C + (size_t)(bm + wr * 32 + m * 16 + cr) * N + (bn + wc * 32 + n * 16 + cc);
#pragma unroll
      for (int r = 0; r < 4; ++r) cp[(size_t)r * N] = acc[m][n][r];
    }
}

__global__ __launch_bounds__(256) void gemm_bf16(
    const unsigned short* __restrict__ A, const unsigned short* __restrict__ W,
    float* __restrict__ C, int N, int K)
{
  gemm_mfma_body(A, W, C, N, K, blockIdx.y * 64, blockIdx.x * 64, threadIdx.x);
}

struct W6 { const unsigned short* w[6]; };

__global__ __launch_bounds__(256) void gemm_bf16_kv6(
    const unsigned short* __restrict__ A, W6 p6, float* __restrict__ Cbase)
{
  gemm_mfma_body(A, p6.w[blockIdx.z], Cbase + (size_t)blockIdx.z * (SLEN * 256),
                 256, 1024, blockIdx.y * 64, blockIdx.x * 64, threadIdx.x);
}

// ---------------- RoPE ----------------
__global__ void rope_q_kernel(float* __restrict__ buf)
{
  const int s = blockIdx.x;
  const int t = threadIdx.x;
  const int c = t >> 5, d = t & 31;
  float* p = buf + (size_t)s * 1024 + c * 64;
  const float inv = powf(10000.f, -(float)d * (1.f / 32.f));
  float sn, cs;
  sincosf((float)s * inv, &sn, &cs);
  const float x1 = p[d], x2 = p[d + 32];
  p[d]      = x1 * cs - x2 * sn;
  p[d + 32] = x1 * sn + x2 * cs;
}

__global__ void rope_k_kernel(float* __restrict__ kvbase)
{
  const int s = blockIdx.x;
  const int which = blockIdx.y;
  const int t = threadIdx.x;
  const int c = t >> 5, d = t & 31;
  float* p = kvbase + (size_t)which * 2 * (SLEN * 256) + (size_t)s * 256 + c * 64;
  const float inv = powf(10000.f, -(float)d * (1.f / 32.f));
  float sn, cs;
  sincosf((float)s * inv, &sn, &cs);
  const float x1 = p[d], x2 = p[d + 32];
  p[d]      = x1 * cs - x2 * sn;
  p[d + 32] = x1 * sn + x2 * cs;
}

// ---------------- cmp pooling -> padded bf16 (Kc row-major, Vc transposed) ----------------
__global__ __launch_bounds__(64) void pool_kernel(
    const float* __restrict__ k_cmp, const float* __restrict__ v_cmp,
    unsigned short* __restrict__ KcB, unsigned short* __restrict__ VcTB)
{
  const int c = blockIdx.x;   // 0..63 (63 = zero pad)
  const int g = blockIdx.y;
  const int d = threadIdx.x;
  float ak = 0.f, av = 0.f;
  if (c < SCMP) {
    for (int j = 0; j < 32; ++j) {
      const size_t off = (size_t)(c * 16 + j) * 256 + g * 64 + d;
      ak += k_cmp[off];
      av += v_cmp[off];
    }
    ak *= (1.f / 32.f); av *= (1.f / 32.f);
  }
  KcB[(size_t)(g * 64 + c) * 64 + d] = f2bf(ak);
  VcTB[(size_t)(g * 64 + d) * 64 + c] = f2bf(av);
}

// ---------------- V transpose: [1024][256] f32 -> [256][1024] bf16 ----------------
__global__ __launch_bounds__(256) void transpose_v(
    const float* __restrict__ v0, const float* __restrict__ v1,
    unsigned short* __restrict__ t0, unsigned short* __restrict__ t1)
{
  const float* src = blockIdx.z ? v1 : v0;
  unsigned short* dst = blockIdx.z ? t1 : t0;
  __shared__ float tile[32][33];
  const int tr = blockIdx.x * 32, tc = blockIdx.y * 32;
  const int r = threadIdx.x >> 5, c = threadIdx.x & 31;
#pragma unroll
  for (int i = 0; i < 4; ++i)
    tile[r + i * 8][c] = src[(size_t)(tr + r + i * 8) * 256 + tc + c];
  __syncthreads();
#pragma unroll
  for (int i = 0; i < 4; ++i)
    dst[(size_t)(tc + r + i * 8) * 1024 + tr + c] = f2bf(tile[c][r + i * 8]);
}

// ---------------- gating MLP ----------------
__global__ __launch_bounds__(64) void gate_kernel(
    const float* __restrict__ q, const float* __restrict__ g1w, const float* __restrict__ g1b,
    const float* __restrict__ g2w, const float* __restrict__ g2b, float* __restrict__ gates)
{
  const int s = blockIdx.x, g = blockIdx.y;
  const int t = threadIdx.x;
  __shared__ float qg[64], h1[32];
  const float* qb = q + (size_t)(s * 16 + g * 4) * 64;
  qg[t] = (qb[t] + qb[64 + t] + qb[128 + t] + qb[192 + t]) * 0.25f;
  __syncthreads();
  if (t < 32) {
    float a = g1b[t];
    for (int d = 0; d < 64; ++d) a += qg[d] * g1w[t * 64 + d];
    h1[t] = a / (1.f + expf(-a));
  }
  __syncthreads();
  if (t == 0) {
    float gl[3];
    for (int r = 0; r < 3; ++r) {
      float a = g2b[r];
      for (int j = 0; j < 32; ++j) a += h1[j] * g2w[r * 32 + j];
      gl[r] = a;
    }
    const float m1 = fmaxf(gl[0], fmaxf(gl[1], gl[2]));
    const float e0 = expf(gl[0] - m1), e1 = expf(gl[1] - m1), e2 = expf(gl[2] - m1);
    const float inv = 1.f / (e0 + e1 + e2);
    float p0 = e0 * inv, p1 = e1 * inv, p2 = e2 * inv;
    int am = 0; float best = gl[0];
    if (gl[1] > best) { best = gl[1]; am = 1; }
    if (gl[2] > best) { best = gl[2]; am = 2; }
    float second = -INFINITY;
    for (int r = 0; r < 3; ++r) if (r != am) second = fmaxf(second, gl[r]);
    if (best - second > 50.f) { p0 = (am == 0) ? 1.f : 0.f; p1 = (am == 1) ? 1.f : 0.f; p2 = (am == 2) ? 1.f : 0.f; }
    float* o = gates + (size_t)(s * 4 + g) * 3;
    o[0] = p0; o[1] = p1; o[2] = p2;
  }
}

// ---------------- MFMA NSA attention ----------------
// grid = (32 qtiles, 4 groups, 2): z=0 -> cmp+sel (writes Ocs), z=1 -> win (writes Owin).
// 8 waves = 4 heads x 2 row-halves. Per-branch tile loop is a 2-stage pipeline:
// prologue stage -> { stage(next, buf^1); compute(cur); __syncthreads(); }.
__device__ __forceinline__ void attn_stage(
    const unsigned short* ksrc, const unsigned short* vsrc,
    unsigned short* Kbuf, unsigned short* Vbuf, int tid)
{
  gload_lds16(ksrc, Kbuf + tid * 8);
  gload_lds16(vsrc, Vbuf + tid * 8);
}

// BR: 0=cmp, 1=sel (per-row 16-bit block mask), 2=win (sliding window).
template<int BR>
__device__ __forceinline__ void attn_compute(
    int b, int s0, int w, int l,
    bf16x8 aq0, bf16x8 aq1,
    float (&m)[4], float (&ls)[4], f32x4 (&Oa)[4],
    const unsigned short* Klds, const unsigned short* Vlds,
    float (*Pw)[76], float (*lcS)[16], const unsigned* selmaskS)
{
  const int kg = l >> 4, lr = l & 15;
  f32x4 sc[4];
#pragma unroll
  for (int f = 0; f < 4; ++f) {
    sc[f] = (f32x4){0.f, 0.f, 0.f, 0.f};
    sc[f] = __builtin_amdgcn_mfma_f32_16x16x32_bf16(
        aq0, *(const bf16x8*)(Klds + (f * 2 + 0) * 512 + l * 8), sc[f], 0, 0, 0);
    sc[f] = __builtin_amdgcn_mfma_f32_16x16x32_bf16(
        aq1, *(const bf16x8*)(Klds + (f * 2 + 1) * 512 + l * 8), sc[f], 0, 0, 0);
  }

  float mnew[4], scale[4], ps[4];
#pragma unroll
  for (int r = 0; r < 4; ++r) {
    const int lrow = (w & 1) * 16 + kg * 4 + r;
    const int sr = s0 + lrow;
#pragma unroll
    for (int f = 0; f < 4; ++f) {
      const int tok = b * 64 + 16 * f + lr;
      bool ok;
      if (BR == 0)      ok = (tok < SCMP) && (tok * 16 + 31 <= sr);
      else if (BR == 1) ok = ((selmaskS[lrow] >> b) & 1u) && (tok <= sr);
      else              ok = (tok <= sr) && (tok > sr - WWIN);
      sc[f][r] = ok ? sc[f][r] * SCALEF : -1e30f;
    }
  }
  float tm[4];
#pragma unroll
  for (int r = 0; r < 4; ++r) {
    tm[r] = fmaxf(fmaxf(sc[0][r], sc[1][r]), fmaxf(sc[2][r], sc[3][r]));
    tm[r] = fmaxf(tm[r], __shfl_xor(tm[r], 1));
    tm[r] = fmaxf(tm[r], __shfl_xor(tm[r], 2));
    tm[r] = fmaxf(tm[r], __shfl_xor(tm[r], 4));
    tm[r] = fmaxf(tm[r], __shfl_xor(tm[r], 8));
    mnew[r] = fmaxf(m[r], tm[r]);
    scale[r] = __expf(m[r] - mnew[r]);
    ps[r] = 0.f;
  }
#pragma unroll
  for (int f = 0; f < 4; ++f)
#pragma unroll
    for (int r = 0; r < 4; ++r) {
      const float p = (sc[f][r] > -1e29f) ? __expf(sc[f][r] - mnew[r]) : 0.f;
      Pw[kg * 4 + r][16 * f + lr] = p;
      ps[r] += p;
    }
#pragma unroll
  for (int r = 0; r < 4; ++r) {
    ps[r] += __shfl_xor(ps[r], 1);
    ps[r] += __shfl_xor(ps[r], 2);
    ps[r] += __shfl_xor(ps[r], 4);
    ps[r] += __shfl_xor(ps[r], 8);
    ls[r] = ls[r] * scale[r] + ps[r];
    m[r] = mnew[r];
  }
  if (BR == 0 && lr == 0) {
#pragma unroll
    for (int r = 0; r < 4; ++r) lcS[w][kg * 4 + r] = ls[r];
  }
#pragma unroll
  for (int f = 0; f < 4; ++f) {
    Oa[f][0] *= scale[0]; Oa[f][1] *= scale[1];
    Oa[f][2] *= scale[2]; Oa[f][3] *= scale[3];
  }
  asm volatile("s_waitcnt lgkmcnt(0)" ::: "memory");  // wave's P writes visible to its reads
#pragma unroll
  for (int ks = 0; ks < 2; ++ks) {
    const float4 pa0 = *(const float4*)&Pw[lr][ks * 32 + kg * 8];
    const float4 pa1 = *(const float4*)&Pw[lr][ks * 32 + kg * 8 + 4];
    const bf16x8 pa = pack8(pa0, pa1);
#pragma unroll
    for (int f = 0; f < 4; ++f)
      Oa[f] = __builtin_amdgcn_mfma_f32_16x16x32_bf16(
          pa, *(const bf16x8*)(Vlds + (f * 2 + ks) * 512 + l * 8), Oa[f], 0, 0, 0);
  }
}

__global__ __launch_bounds__(512) void attn_mfma_kernel(
    const unsigned short* __restrict__ qb,     // [S][16][64] bf16
    const unsigned short* __restrict__ kselb,  // [S][256] bf16
    const unsigned short* __restrict__ vselT,  // [256][S] bf16
    const unsigned short* __restrict__ kwinb,
    const unsigned short* __restrict__ vwinT,
    const unsigned short* __restrict__ KcB,    // [g*64+c][64] bf16 (c=63 pad)
    const unsigned short* __restrict__ VcTB,   // [g*64+d][64] bf16
    const float* __restrict__ gates,           // [S][4][3]
    float* __restrict__ Ocs,                   // [S][16][64] f32 (cmp+sel, gated)
    float* __restrict__ Owin)                  // [S][16][64] f32 (win, gated)
{
  const int qt = blockIdx.x;
  const int g  = blockIdx.y;
  const int z  = blockIdx.z;
  const int s0 = qt * QBLK;
  const int tid = threadIdx.x;
  const int w = tid >> 6, l = tid & 63;
  const int h = w >> 1;
  const int kg = l >> 4, lr = l & 15;

  __shared__ unsigned short Klds[2][4096];
  __shared__ unsigned short Vlds[2][4096];
  __shared__ float Plds[8][16][76];
  __shared__ float lgS[QBLK][16];
  __shared__ float lcS[8][16];
  __shared__ unsigned selmaskS[QBLK];
  __shared__ int selListS[16];
  __shared__ int nselS;

  if (tid < QBLK) selmaskS[tid] = 0u;

  const int sf = tid >> 7, sks = (tid >> 6) & 1, skh = (tid >> 4) & 3, stk = tid & 15;

  const int sq = s0 + (w & 1) * 16 + lr;
  const unsigned short* qrow = qb + (size_t)(sq * 16 + g * 4 + h) * 64;
  const bf16x8 aq0 = *(const bf16x8*)(qrow + kg * 8);
  const bf16x8 aq1 = *(const bf16x8*)(qrow + 32 + kg * 8);

  float gv[3][4];
#pragma unroll
  for (int r = 0; r < 4; ++r) {
    const int sr = s0 + (w & 1) * 16 + kg * 4 + r;
    const float* gp = gates + (size_t)(sr * 4 + g) * 3;
    gv[0][r] = gp[0]; gv[1][r] = gp[1]; gv[2][r] = gp[2];
  }

  f32x4 Ot[4];
#pragma unroll
  for (int f = 0; f < 4; ++f) Ot[f] = (f32x4){0.f, 0.f, 0.f, 0.f};

  float m[4], ls[4];
  f32x4 Oa[4];

#define ARESET() do { \
    _Pragma("unroll") for (int r = 0; r < 4; ++r) { m[r] = -1e30f; ls[r] = 0.f; } \
    _Pragma("unroll") for (int f = 0; f < 4; ++f) Oa[f] = (f32x4){0.f,0.f,0.f,0.f}; \
  } while (0)
#define AFINAL(bi) do { \
    _Pragma("unroll") for (int f = 0; f < 4; ++f) \
    _Pragma("unroll") for (int r = 0; r < 4; ++r) \
      Ot[f][r] += gv[bi][r] * ((ls[r] > 0.f) ? (Oa[f][r] / ls[r]) : 0.f); \
  } while (0)

  const int bmax = (s0 + QBLK - 1) >> 6;

  if (z == 0) {
    // ---- cmp branch (single tile) ----
    ARESET();
    attn_stage(KcB  + (size_t)(g * 64 + 16 * sf + stk) * 64 + sks * 32 + skh * 8,
               VcTB + (size_t)(g * 64 + 16 * sf + stk) * 64 + sks * 32 + skh * 8,
               Klds[0], Vlds[0], tid);
    __syncthreads();
    attn_compute<0>(0, s0, w, l, aq0, aq1, m, ls, Oa, Klds[0], Vlds[0],
                    Plds[w], lcS, selmaskS);
    AFINAL(0);
    __syncthreads();   // cmp P + lcS visible block-wide

    // ---- selection: p_slc (M_MAP inline), lg, top-8 ----
    {
      const int row = tid >> 4, mm = tid & 15;
      const int sr = s0 + row;
      float psl = 0.f;
#pragma unroll
      for (int hh = 0; hh < 4; ++hh) {
        const int wv = hh * 2 + (row >> 4);
        const int r16 = row & 15;
        const float lc = lcS[wv][r16];
        if (lc > 0.f) {
          const int cb = 4 * mm;
          float a = Plds[wv][r16][cb] + Plds[wv][r16][cb + 1] + Plds[wv][r16][cb + 2];
          if (cb >= 1)         a += 0.5f * Plds[wv][r16][cb - 1];
          if (cb + 3 < SCMP)   a += 0.5f * Plds[wv][r16][cb + 3];
          psl += a / lc;
        }
      }
      const bool causal = (mm << 6) <= sr;
      const bool forced = (mm == 0) || (mm == (sr >> 6));
      lgS[row][mm] = causal ? (psl + (forced ? 1e6f : 0.f)) : -1e9f;
    }
    __syncthreads();
    {
      const int row = tid >> 4, mm = tid & 15;
      const float my = lgS[row][mm];
      int rank = 0;
#pragma unroll
      for (int m2 = 0; m2 < 16; ++m2) {
        const float v = lgS[row][m2];
        if (v > my || (v == my && m2 < mm)) ++rank;
      }
      if (rank < NSELK) atomicOr(&selmaskS[row], 1u << mm);
    }
    __syncthreads();
    if (tid == 0) {
      unsigned u = 0;
      for (int r = 0; r < QBLK; ++r) u |= selmaskS[r];
      int n = 0;
      for (int b = 0; b < 16; ++b) if ((u >> b) & 1u) selListS[n++] = b;
      nselS = n;
    }
    __syncthreads();
    const int nt = nselS;   // >= 1 (block 0 forced+causal)

    // ---- sel branch: pipelined over selected-block list ----
    ARESET();
    {
      int b0 = selListS[0];
      attn_stage(kselb + (size_t)(b0 * 64 + 16 * sf + stk) * 256 + g * 64 + sks * 32 + skh * 8,
                 vselT + (size_t)(g * 64 + 16 * sf + stk) * 1024 + b0 * 64 + sks * 32 + skh * 8,
                 Klds[0], Vlds[0], tid);
      __syncthreads();
      for (int i = 0; i < nt; ++i) {
        if (i + 1 < nt) {
          const int bn = selListS[i + 1];
          attn_stage(kselb + (size_t)(bn * 64 + 16 * sf + stk) * 256 + g * 64 + sks * 32 + skh * 8,
                     vselT + (size_t)(g * 64 + 16 * sf + stk) * 1024 + bn * 64 + sks * 32 + skh * 8,
                     Klds[(i + 1) & 1], Vlds[(i + 1) & 1], tid);
        }
        attn_compute<1>(selListS[i], s0, w, l, aq0, aq1, m, ls, Oa,
                        Klds[i & 1], Vlds[i & 1], Plds[w], lcS, selmaskS);
        __syncthreads();
      }
    }
    AFINAL(1);

#pragma unroll
    for (int f = 0; f < 4; ++f)
#pragma unroll
      for (int r = 0; r < 4; ++r) {
        const int sr = s0 + (w & 1) * 16 + kg * 4 + r;
        Ocs[(size_t)(sr * 16 + g * 4 + h) * 64 + 16 * f + lr] = Ot[f][r];
      }
  } else {
    // ---- win branch: pipelined over window blocks ----
    ARESET();
    const int blo = (s0 >= (WWIN - 1)) ? ((s0 - (WWIN - 1)) >> 6) : 0;
    const int nt = bmax - blo + 1;
    attn_stage(kwinb + (size_t)(blo * 64 + 16 * sf + stk) * 256 + g * 64 + sks * 32 + skh * 8,
               vwinT + (size_t)(g * 64 + 16 * sf + stk) * 1024 + blo * 64 + sks * 32 + skh * 8,
               Klds[0], Vlds[0], tid);
    __syncthreads();
    for (int i = 0; i < nt; ++i) {
      if (i + 1 < nt) {
        const int bn = blo + i + 1;
        attn_stage(kwinb + (size_t)(bn * 64 + 16 * sf + stk) * 256 + g * 64 + sks * 32 + skh * 8,
                   vwinT + (size_t)(g * 64 + 16 * sf + stk) * 1024 + bn * 64 + sks * 32 + skh * 8,
                   Klds[(i + 1) & 1], Vlds[(i + 1) & 1], tid);
      }
      attn_compute<2>(blo + i, s0, w, l, aq0, aq1, m, ls, Oa,
                      Klds[i & 1], Vlds[i & 1], Plds[w], lcS, selmaskS);
      __syncthreads();
    }
    AFINAL(2);

#pragma unroll
    for (int f = 0; f < 4; ++f)
#pragma unroll
      for (int r = 0; r < 4; ++r) {
        const int sr = s0 + (w & 1) * 16 + kg * 4 + r;
        Owin[(size_t)(sr * 16 + g * 4 + h) * 64 + 16 * f + lr] = Ot[f][r];
      }
  }
#undef ARESET
#undef AFINAL
}

// ---------------- launch ----------------
extern "C" void kernel_launch(void* const* d_in, const int* in_sizes, int n_in,
                              void* d_out, int out_size, void* d_ws, size_t ws_size,
                              hipStream_t stream) {
  const float* x      = (const float*)d_in[0];
  const float* wq     = (const float*)d_in[1];
  const float* wk_sel = (const float*)d_in[2];
  const float* wv_sel = (const float*)d_in[3];
  const float* wk_win = (const float*)d_in[4];
  const float* wv_win = (const float*)d_in[5];
  const float* wk_cmp = (const float*)d_in[6];
  const float* wv_cmp = (const float*)d_in[7];
  const float* w_out  = (const float*)d_in[8];
  const float* g1w    = (const float*)d_in[9];
  const float* g1b    = (const float*)d_in[10];
  const float* g2w    = (const float*)d_in[11];
  const float* g2b    = (const float*)d_in[12];

  float* ws = (float*)d_ws;
  float* q     = ws;                         // 1,048,576 f32
  float* kv    = q + 1048576;                // 6 x 262,144 f32
  float* ksel  = kv;
  float* vsel  = kv + 1 * 262144;
  float* kwin  = kv + 2 * 262144;
  float* vwin  = kv + 3 * 262144;
  float* kcmp  = kv + 4 * 262144;
  float* vcmp  = kv + 5 * 262144;
  float* gts   = kv + 6 * 262144;            // 12,288 f32
  float* Obuf  = gts + 12288;                // 1,048,576 f32
  float* Owin  = kv;                         // alias: ksel..vwin f32 dead after conv/transpose

  unsigned short* xb     = (unsigned short*)(Obuf + 1048576);
  unsigned short* wqb    = xb + 1048576;
  unsigned short* kvwb   = wqb + 1048576;    // 6 x 262,144
  unsigned short* w_outb = kvwb + 6 * 262144;
  unsigned short* q_b    = w_outb + 1048576; // 1,048,576
  unsigned short* kselb  = q_b + 1048576;    // 262,144
  unsigned short* kwinb  = kselb + 262144;
  unsigned short* vselT  = kwinb + 262144;   // 262,144 (transposed)
  unsigned short* vwinT  = vselT + 262144;
  unsigned short* KcB    = vwinT + 262144;   // 16,384
  unsigned short* VcTB   = KcB + 16384;      // 16,384

  // inputs -> bf16
  ConvJobs j1 = {};
  j1.cnt = 9;
  j1.src[0] = x;      j1.dst[0] = (unsigned*)xb;                j1.n4[0] = 262144;
  j1.src[1] = wq;     j1.dst[1] = (unsigned*)wqb;               j1.n4[1] = 262144;
  j1.src[2] = wk_sel; j1.dst[2] = (unsigned*)(kvwb + 0*262144); j1.n4[2] = 65536;
  j1.src[3] = wv_sel; j1.dst[3] = (unsigned*)(kvwb + 1*262144); j1.n4[3] = 65536;
  j1.src[4] = wk_win; j1.dst[4] = (unsigned*)(kvwb + 2*262144); j1.n4[4] = 65536;
  j1.src[5] = wv_win; j1.dst[5] = (unsigned*)(kvwb + 3*262144); j1.n4[5] = 65536;
  j1.src[6] = wk_cmp; j1.dst[6] = (unsigned*)(kvwb + 4*262144); j1.n4[6] = 65536;
  j1.src[7] = wv_cmp; j1.dst[7] = (unsigned*)(kvwb + 5*262144); j1.n4[7] = 65536;
  j1.src[8] = w_out;  j1.dst[8] = (unsigned*)w_outb;            j1.n4[8] = 262144;
  conv_f32_bf16<<<1024, 256, 0, stream>>>(j1);

  // projections
  gemm_bf16<<<dim3(16, 16), 256, 0, stream>>>(xb, wqb, q, 1024, 1024);
  W6 p6 = {{ kvwb + 0*262144, kvwb + 1*262144, kvwb + 2*262144,
             kvwb + 3*262144, kvwb + 4*262144, kvwb + 5*262144 }};
  gemm_bf16_kv6<<<dim3(4, 16, 6), 256, 0, stream>>>(xb, p6, kv);

  // rope
  rope_q_kernel<<<1024, 512, 0, stream>>>(q);
  rope_k_kernel<<<dim3(1024, 3), 128, 0, stream>>>(kv);

  // pooled cmp K/V -> bf16 (padded, V transposed)
  pool_kernel<<<dim3(64, 4), 64, 0, stream>>>(kcmp, vcmp, KcB, VcTB);

  // gates (f32 q)
  gate_kernel<<<dim3(1024, 4), 64, 0, stream>>>(q, g1w, g1b, g2w, g2b, gts);

  // q/k -> bf16
  ConvJobs j2 = {};
  j2.cnt = 3;
  j2.src[0] = q;    j2.dst[0] = (unsigned*)q_b;   j2.n4[0] = 262144;
  j2.src[1] = ksel; j2.dst[1] = (unsigned*)kselb; j2.n4[1] = 65536;
  j2.src[2] = kwin; j2.dst[2] = (unsigned*)kwinb; j2.n4[2] = 65536;
  conv_f32_bf16<<<1024, 256, 0, stream>>>(j2);

  // v -> transposed bf16
  transpose_v<<<dim3(32, 8, 2), 256, 0, stream>>>(vsel, vwin, vselT, vwinT);

  // fused MFMA NSA attention (z=0: cmp+sel, z=1: win)
  attn_mfma_kernel<<<dim3(32, 4, 2), 512, 0, stream>>>(
      q_b, kselb, vselT, kwinb, vwinT, KcB, VcTB, gts, Obuf, Owin);

  // combine + output projection
  conv_add_bf16<<<1024, 256, 0, stream>>>(Obuf, Owin, (uint2*)xb);
  gemm_bf16<<<dim3(16, 16), 256, 0, stream>>>(xb, w_outb, (float*)d_out, 1024, 1024);
}

// Round 5
// 122.425 us; speedup vs baseline: 4.5155x; 1.2289x over previous
//
#include <hip/hip_runtime.h>
#include <math.h>

// ---------------- problem constants ----------------
#define SLEN   1024
#define NGRP   4
#define NHEAD  16
#define HPGRP  4
#define DKV    64
#define SCMP   63     // (1024-32)/16+1
#define NBLK   16
#define NSELK  8
#define WWIN   512
#define SCALEF 0.125f // 1/sqrt(64)
#define QBLK   16
#define EXPOFF 8.0f   // fixed softmax offset: exp(sc-8); scores bounded << 80

typedef __attribute__((ext_vector_type(4))) float f32x4;
typedef __attribute__((ext_vector_type(8))) short bf16x8;

// ---------------- f32 -> bf16 (RNE) helpers ----------------
__device__ __forceinline__ unsigned short f2bf(float f) {
  unsigned u = __float_as_uint(f);
  u += 0x7FFFu + ((u >> 16) & 1u);
  return (unsigned short)(u >> 16);
}
__device__ __forceinline__ unsigned pack2(float a, float b) {
  return (unsigned)f2bf(a) | ((unsigned)f2bf(b) << 16);
}
__device__ __forceinline__ bf16x8 pack8(float4 a, float4 b) {
  union { bf16x8 v; unsigned u[4]; } u;
  u.u[0] = pack2(a.x, a.y); u.u[1] = pack2(a.z, a.w);
  u.u[2] = pack2(b.x, b.y); u.u[3] = pack2(b.z, b.w);
  return u.v;
}

struct ConvJobs {
  const float* src[9];
  unsigned* dst[9];
  int n4[9];
  int cnt;
};

__global__ __launch_bounds__(256) void conv_f32_bf16(ConvJobs jb) {
  const int stride = gridDim.x * blockDim.x;
  for (int t = 0; t < jb.cnt; ++t) {
    const float4* s = (const float4*)jb.src[t];
    uint2* d = (uint2*)jb.dst[t];
    const int n4 = jb.n4[t];
    for (int i = blockIdx.x * blockDim.x + threadIdx.x; i < n4; i += stride) {
      const float4 v = s[i];
      uint2 o;
      o.x = pack2(v.x, v.y);
      o.y = pack2(v.z, v.w);
      d[i] = o;
    }
  }
}

// sum two f32 buffers -> bf16
__global__ __launch_bounds__(256) void conv_add_bf16(
    const float* __restrict__ a, const float* __restrict__ b, uint2* __restrict__ d)
{
  const int i = blockIdx.x * 256 + threadIdx.x;
  const float4 va = ((const float4*)a)[i];
  const float4 vb = ((const float4*)b)[i];
  uint2 o;
  o.x = pack2(va.x + vb.x, va.y + vb.y);
  o.y = pack2(va.z + vb.z, va.w + vb.w);
  d[i] = o;
}

// ---------------- async global->LDS 16B ----------------
__device__ __forceinline__ void gload_lds16(const unsigned short* g, unsigned short* l) {
  __builtin_amdgcn_global_load_lds(
      (const __attribute__((address_space(1))) void*)g,
      (__attribute__((address_space(3))) void*)l, 16, 0, 0);
}

// ---------------- bf16 MFMA GEMM: C[M][N] = A[M][K] @ W[N][K]^T ----------------
__device__ __forceinline__ void gemm_mfma_body(
    const unsigned short* __restrict__ A, const unsigned short* __restrict__ W,
    float* __restrict__ C, int N, int K, int bm, int bn, int tid)
{
  __shared__ unsigned short As[3][2048];
  __shared__ unsigned short Bs[3][2048];
  const int lane = tid & 63;
  const int wave = tid >> 6;
  const int wr = wave >> 1, wc = wave & 1;

  const int sub = tid >> 6;
  const int kh  = (tid >> 4) & 3;
  const int row = tid & 15;
  const unsigned short* aSrc = A + (size_t)(bm + sub * 16 + row) * K + kh * 8;
  const unsigned short* bSrc = W + (size_t)(bn + sub * 16 + row) * K + kh * 8;
  const int slot = tid * 8;

  f32x4 acc[2][2];
#pragma unroll
  for (int m = 0; m < 2; ++m)
#pragma unroll
    for (int n = 0; n < 2; ++n) acc[m][n] = (f32x4){0.f, 0.f, 0.f, 0.f};

  const int NIT = K >> 5;
  gload_lds16(aSrc + 0,  &As[0][slot]);
  gload_lds16(bSrc + 0,  &Bs[0][slot]);
  gload_lds16(aSrc + 32, &As[1][slot]);
  gload_lds16(bSrc + 32, &Bs[1][slot]);

  for (int i = 0; i < NIT; ++i) {
    __builtin_amdgcn_sched_barrier(0);
    if (i + 1 < NIT) asm volatile("s_waitcnt vmcnt(2)" ::: "memory");
    else             asm volatile("s_waitcnt vmcnt(0)" ::: "memory");
    __builtin_amdgcn_s_barrier();
    __builtin_amdgcn_sched_barrier(0);
    if (i + 2 < NIT) {
      const int nb = (i + 2) % 3;
      gload_lds16(aSrc + (i + 2) * 32, &As[nb][slot]);
      gload_lds16(bSrc + (i + 2) * 32, &Bs[nb][slot]);
    }
    const int cur = i % 3;
    const bf16x8 a0 = *(const bf16x8*)(&As[cur][(wr * 2 + 0) * 512 + lane * 8]);
    const bf16x8 a1 = *(const bf16x8*)(&As[cur][(wr * 2 + 1) * 512 + lane * 8]);
    const bf16x8 b0 = *(const bf16x8*)(&Bs[cur][(wc * 2 + 0) * 512 + lane * 8]);
    const bf16x8 b1 = *(const bf16x8*)(&Bs[cur][(wc * 2 + 1) * 512 + lane * 8]);
    acc[0][0] = __builtin_amdgcn_mfma_f32_16x16x32_bf16(a0, b0, acc[0][0], 0, 0, 0);
    acc[0][1] = __builtin_amdgcn_mfma_f32_16x16x32_bf16(a0, b1, acc[0][1], 0, 0, 0);
    acc[1][0] = __builtin_amdgcn_mfma_f32_16x16x32_bf16(a1, b0, acc[1][0], 0, 0, 0);
    acc[1][1] = __builtin_amdgcn_mfma_f32_16x16x32_bf16(a1, b1, acc[1][1], 0, 0, 0);
  }

  const int cr = (lane >> 4) * 4;
  const int cc = lane & 15;
#pragma unroll
  for (int m = 0; m < 2; ++m)
#pragma unroll
    for (int n = 0; n < 2; ++n) {
      float* cp = C + (size_t)(bm + wr * 32 + m * 16 + cr) * N + (bn + wc * 32 + n * 16 + cc);
#pragma unroll
      for (int r = 0; r < 4; ++r) cp[(size_t)r * N] = acc[m][n][r];
    }
}

__global__ __launch_bounds__(256) void gemm_bf16(
    const unsigned short* __restrict__ A, const unsigned short* __restrict__ W,
    float* __restrict__ C, int N, int K)
{
  gemm_mfma_body(A, W, C, N, K, blockIdx.y * 64, blockIdx.x * 64, threadIdx.x);
}

struct W6 { const unsigned short* w[6]; };

__global__ __launch_bounds__(256) void gemm_bf16_kv6(
    const unsigned short* __restrict__ A, W6 p6, float* __restrict__ Cbase)
{
  gemm_mfma_body(A, p6.w[blockIdx.z], Cbase + (size_t)blockIdx.z * (SLEN * 256),
                 256, 1024, blockIdx.y * 64, blockIdx.x * 64, threadIdx.x);
}

// ---------------- fused prep: rope q/ksel/kwin + q_b bf16 + gates + sincos table ----------------
__global__ __launch_bounds__(256) void prep_kernel(
    const float* __restrict__ qf,      // [S][1024] raw q projection
    const float* __restrict__ kself,   // [S][256]
    const float* __restrict__ kwinf,   // [S][256]
    const float* __restrict__ g1w, const float* __restrict__ g1b,
    const float* __restrict__ g2w, const float* __restrict__ g2b,
    unsigned short* __restrict__ q_b,
    unsigned short* __restrict__ kselb, unsigned short* __restrict__ kwinb,
    float* __restrict__ gates, float2* __restrict__ tab)
{
  const int s = blockIdx.x, t = threadIdx.x;
  __shared__ float csS[32], snS[32];
  __shared__ float qs[1024];
  __shared__ float qgS[4][64];
  __shared__ float h1S[4][32];
  __shared__ float glS[4][3];
  if (t < 32) {
    const float inv = powf(10000.f, -(float)t * (1.f / 32.f));
    float sn, cs;
    sincosf((float)s * inv, &sn, &cs);
    csS[t] = cs; snS[t] = sn;
    tab[s * 32 + t] = make_float2(cs, sn);
  }
  __syncthreads();
  // rope q: thread -> head t>>4, 2 pairs
  {
    const int ht = t >> 4;
    const float* qr = qf + (size_t)s * 1024 + ht * 64;
#pragma unroll
    for (int i = 0; i < 2; ++i) {
      const int dd = (t & 15) * 2 + i;
      const float x1 = qr[dd], x2 = qr[dd + 32];
      qs[ht * 64 + dd]      = x1 * csS[dd] - x2 * snS[dd];
      qs[ht * 64 + dd + 32] = x1 * snS[dd] + x2 * csS[dd];
    }
  }
  // rope ksel (t<128) / kwin (t>=128): 1 pair each
  {
    const int which = t >> 7;
    const int g = (t >> 5) & 3, dd = t & 31;
    const float* src = (which ? kwinf : kself) + (size_t)s * 256 + g * 64;
    unsigned short* dst = (which ? kwinb : kselb) + (size_t)s * 256 + g * 64;
    const float x1 = src[dd], x2 = src[dd + 32];
    dst[dd]      = f2bf(x1 * csS[dd] - x2 * snS[dd]);
    dst[dd + 32] = f2bf(x1 * snS[dd] + x2 * csS[dd]);
  }
  __syncthreads();
  // q_b: 4 bf16 per thread
  {
    uint2 o;
    o.x = pack2(qs[t * 4 + 0], qs[t * 4 + 1]);
    o.y = pack2(qs[t * 4 + 2], qs[t * 4 + 3]);
    *(uint2*)(q_b + (size_t)s * 1024 + t * 4) = o;
  }
  // qg: mean over 4 heads
  {
    const int g = t >> 6, d = t & 63;
    qgS[g][d] = (qs[g * 256 + d] + qs[g * 256 + 64 + d] +
                 qs[g * 256 + 128 + d] + qs[g * 256 + 192 + d]) * 0.25f;
  }
  __syncthreads();
  if (t < 128) {
    const int g = t >> 5, j = t & 31;
    float a = g1b[j];
    for (int d = 0; d < 64; ++d) a += qgS[g][d] * g1w[j * 64 + d];
    h1S[g][j] = a / (1.f + expf(-a));
  }
  __syncthreads();
  if (t < 16) {
    const int g = t >> 2, rr = t & 3;
    if (rr < 3) {
      float a = g2b[rr];
      for (int j = 0; j < 32; ++j) a += h1S[g][j] * g2w[rr * 32 + j];
      glS[g][rr] = a;
    }
  }
  __syncthreads();
  if (t < 4) {
    const int g = t;
    const float gl0 = glS[g][0], gl1 = glS[g][1], gl2 = glS[g][2];
    const float m1 = fmaxf(gl0, fmaxf(gl1, gl2));
    const float e0 = expf(gl0 - m1), e1 = expf(gl1 - m1), e2 = expf(gl2 - m1);
    const float inv = 1.f / (e0 + e1 + e2);
    float p0 = e0 * inv, p1 = e1 * inv, p2 = e2 * inv;
    int am = 0; float best = gl0;
    if (gl1 > best) { best = gl1; am = 1; }
    if (gl2 > best) { best = gl2; am = 2; }
    float second = -INFINITY;
    if (am != 0) second = fmaxf(second, gl0);
    if (am != 1) second = fmaxf(second, gl1);
    if (am != 2) second = fmaxf(second, gl2);
    if (best - second > 50.f) {
      p0 = (am == 0) ? 1.f : 0.f; p1 = (am == 1) ? 1.f : 0.f; p2 = (am == 2) ? 1.f : 0.f;
    }
    float* o = gates + (size_t)(s * 4 + g) * 3;
    o[0] = p0; o[1] = p1; o[2] = p2;
  }
}

// ---------------- cmp pooling (rope inline via table) -> padded bf16 ----------------
__global__ __launch_bounds__(64) void pool_kernel(
    const float* __restrict__ kcmp, const float* __restrict__ vcmp,
    const float2* __restrict__ tab,
    unsigned short* __restrict__ KcB, unsigned short* __restrict__ VcTB)
{
  const int c = blockIdx.x;   // 0..63 (63 = zero pad)
  const int g = blockIdx.y;
  const int d = threadIdx.x;
  float ak = 0.f, av = 0.f;
  if (c < SCMP) {
    const int d2 = d & 31;
    for (int j = 0; j < 32; ++j) {
      const int pos = c * 16 + j;
      const float2 t2 = tab[pos * 32 + d2];
      const float k1 = kcmp[(size_t)pos * 256 + g * 64 + d2];
      const float k2 = kcmp[(size_t)pos * 256 + g * 64 + d2 + 32];
      ak += (d < 32) ? (k1 * t2.x - k2 * t2.y) : (k1 * t2.y + k2 * t2.x);
      av += vcmp[(size_t)pos * 256 + g * 64 + d];
    }
    ak *= (1.f / 32.f); av *= (1.f / 32.f);
  }
  KcB[(size_t)(g * 64 + c) * 64 + d] = f2bf(ak);
  VcTB[(size_t)(g * 64 + d) * 64 + c] = f2bf(av);
}

// ---------------- V transpose: [1024][256] f32 -> [256][1024] bf16 ----------------
__global__ __launch_bounds__(256) void transpose_v(
    const float* __restrict__ v0, const float* __restrict__ v1,
    unsigned short* __restrict__ t0, unsigned short* __restrict__ t1)
{
  const float* src = blockIdx.z ? v1 : v0;
  unsigned short* dst = blockIdx.z ? t1 : t0;
  __shared__ float tile[32][33];
  const int tr = blockIdx.x * 32, tc = blockIdx.y * 32;
  const int r = threadIdx.x >> 5, c = threadIdx.x & 31;
#pragma unroll
  for (int i = 0; i < 4; ++i)
    tile[r + i * 8][c] = src[(size_t)(tr + r + i * 8) * 256 + tc + c];
  __syncthreads();
#pragma unroll
  for (int i = 0; i < 4; ++i)
    dst[(size_t)(tc + r + i * 8) * 1024 + tr + c] = f2bf(tile[c][r + i * 8]);
}

// ---------------- MFMA NSA attention ----------------
// grid = (64 qtiles of 16 rows, 4 groups, 2): z=0 -> cmp+sel (Ocs), z=1 -> win (Owin).
// 4 waves = 4 heads; wave owns 16 q-rows. Fixed-offset softmax (no running max),
// denominator deferred to one reduce per branch. 2-buffer pipelined staging.
__device__ __forceinline__ void stage_tile(
    const unsigned short* kbase, int krow,
    const unsigned short* vbase, int vrow,
    unsigned short* Kb, unsigned short* Vb, int tid)
{
#pragma unroll
  for (int i = 0; i < 2; ++i) {
    const int t2 = tid + i * 256;
    const int sf = t2 >> 7, sks = (t2 >> 6) & 1, skh = (t2 >> 4) & 3, stk = t2 & 15;
    gload_lds16(kbase + (size_t)(16 * sf + stk) * krow + sks * 32 + skh * 8, Kb + t2 * 8);
    gload_lds16(vbase + (size_t)(16 * sf + stk) * vrow + sks * 32 + skh * 8, Vb + t2 * 8);
  }
}

// BR: 0=cmp, 1=sel (per-row 16-bit block mask), 2=win (sliding window)
template<int BR>
__device__ __forceinline__ void attn_compute(
    int b, int s0, int l,
    bf16x8 aq0, bf16x8 aq1,
    float (&ps)[4], f32x4 (&Oa)[4],
    const unsigned short* Klds, const unsigned short* Vlds,
    float (*Pw)[68], const unsigned* selmaskS)
{
  const int kg = l >> 4, lr = l & 15;
  f32x4 sc[4];
  __builtin_amdgcn_s_setprio(1);
#pragma unroll
  for (int f = 0; f < 4; ++f) {
    sc[f] = (f32x4){0.f, 0.f, 0.f, 0.f};
    sc[f] = __builtin_amdgcn_mfma_f32_16x16x32_bf16(
        aq0, *(const bf16x8*)(Klds + (f * 2 + 0) * 512 + l * 8), sc[f], 0, 0, 0);
    sc[f] = __builtin_amdgcn_mfma_f32_16x16x32_bf16(
        aq1, *(const bf16x8*)(Klds + (f * 2 + 1) * 512 + l * 8), sc[f], 0, 0, 0);
  }
  __builtin_amdgcn_s_setprio(0);

#pragma unroll
  for (int r = 0; r < 4; ++r) {
    const int lrow = kg * 4 + r;
    const int sr = s0 + lrow;
#pragma unroll
    for (int f = 0; f < 4; ++f) {
      const int tok = b * 64 + 16 * f + lr;
      bool ok;
      if (BR == 0)      ok = (tok < SCMP) && (tok * 16 + 31 <= sr);
      else if (BR == 1) ok = ((selmaskS[lrow] >> b) & 1u) && (tok <= sr);
      else              ok = (tok <= sr) && (tok > sr - WWIN);
      const float p = ok ? __expf(sc[f][r] * SCALEF - EXPOFF) : 0.f;
      Pw[lrow][16 * f + lr] = p;
      ps[r] += p;
    }
  }
  asm volatile("s_waitcnt lgkmcnt(0)" ::: "memory");  // wave's P writes visible
#pragma unroll
  for (int ks = 0; ks < 2; ++ks) {
    const float4 pa0 = *(const float4*)&Pw[lr][ks * 32 + kg * 8];
    const float4 pa1 = *(const float4*)&Pw[lr][ks * 32 + kg * 8 + 4];
    const bf16x8 pa = pack8(pa0, pa1);
    __builtin_amdgcn_s_setprio(1);
#pragma unroll
    for (int f = 0; f < 4; ++f)
      Oa[f] = __builtin_amdgcn_mfma_f32_16x16x32_bf16(
          pa, *(const bf16x8*)(Vlds + (f * 2 + ks) * 512 + l * 8), Oa[f], 0, 0, 0);
    __builtin_amdgcn_s_setprio(0);
  }
}

__global__ __launch_bounds__(256) void attn_mfma_kernel(
    const unsigned short* __restrict__ qb,     // [S][16][64] bf16 (roped)
    const unsigned short* __restrict__ kselb,  // [S][256] bf16 (roped)
    const unsigned short* __restrict__ vselT,  // [256][S] bf16
    const unsigned short* __restrict__ kwinb,
    const unsigned short* __restrict__ vwinT,
    const unsigned short* __restrict__ KcB,    // [g*64+c][64] bf16
    const unsigned short* __restrict__ VcTB,   // [g*64+d][64] bf16
    const float* __restrict__ gates,           // [S][4][3]
    float* __restrict__ Ocs, float* __restrict__ Owin)
{
  const int qt = blockIdx.x;
  const int g  = blockIdx.y;
  const int z  = blockIdx.z;
  const int s0 = qt * QBLK;
  const int tid = threadIdx.x;
  const int w = tid >> 6, l = tid & 63;    // w = head
  const int kg = l >> 4, lr = l & 15;
  const int bmax = s0 >> 6;                // (s0+row)>>6, same for all rows

  __shared__ unsigned short Klds[2][4096];
  __shared__ unsigned short Vlds[2][4096];
  __shared__ float Plds[4][16][68];
  __shared__ float lgS[QBLK][16];
  __shared__ float lcS[4][16];
  __shared__ unsigned selmaskS[QBLK];
  __shared__ int selListS[16];
  __shared__ int nselS;

  if (tid < QBLK) selmaskS[tid] = 0u;

  // Q A-fragments: row = lr, k-chunks kg*8 / 32+kg*8
  const int sq = s0 + lr;
  const unsigned short* qrow = qb + (size_t)(sq * 16 + g * 4 + w) * 64;
  const bf16x8 aq0 = *(const bf16x8*)(qrow + kg * 8);
  const bf16x8 aq1 = *(const bf16x8*)(qrow + 32 + kg * 8);

  float gv[3][4];
#pragma unroll
  for (int r = 0; r < 4; ++r) {
    const int sr = s0 + kg * 4 + r;
    const float* gp = gates + (size_t)(sr * 4 + g) * 3;
    gv[0][r] = gp[0]; gv[1][r] = gp[1]; gv[2][r] = gp[2];
  }

  f32x4 Ot[4];
#pragma unroll
  for (int f = 0; f < 4; ++f) Ot[f] = (f32x4){0.f, 0.f, 0.f, 0.f};

  float ps[4], ls[4];
  f32x4 Oa[4];

#define ARESET() do { \
    _Pragma("unroll") for (int r = 0; r < 4; ++r) ps[r] = 0.f; \
    _Pragma("unroll") for (int f = 0; f < 4; ++f) Oa[f] = (f32x4){0.f,0.f,0.f,0.f}; \
  } while (0)
#define REDUCE_LS() do { \
    _Pragma("unroll") for (int r = 0; r < 4; ++r) { \
      ls[r] = ps[r]; \
      ls[r] += __shfl_xor(ls[r], 1); ls[r] += __shfl_xor(ls[r], 2); \
      ls[r] += __shfl_xor(ls[r], 4); ls[r] += __shfl_xor(ls[r], 8); } \
  } while (0)
#define AFINAL(bi) do { \
    _Pragma("unroll") for (int f = 0; f < 4; ++f) \
    _Pragma("unroll") for (int r = 0; r < 4; ++r) \
      Ot[f][r] += gv[bi][r] * ((ls[r] > 0.f) ? (Oa[f][r] / ls[r]) : 0.f); \
  } while (0)

  if (z == 0) {
    // ---- cmp branch (single tile) ----
    ARESET();
    stage_tile(KcB + (size_t)g * 64 * 64, 64, VcTB + (size_t)g * 64 * 64, 64,
               Klds[0], Vlds[0], tid);
    __syncthreads();
    attn_compute<0>(0, s0, l, aq0, aq1, ps, Oa, Klds[0], Vlds[0], Plds[w], selmaskS);
    REDUCE_LS();
    if ((l & 15) == 0) {
#pragma unroll
      for (int r = 0; r < 4; ++r) lcS[w][kg * 4 + r] = ls[r];
    }
    AFINAL(0);
    __syncthreads();   // cmp P + lcS visible block-wide

    // ---- selection: p_slc (M_MAP inline), lg, top-8 ----
    {
      const int row = tid >> 4, mm = tid & 15;
      float psl = 0.f;
#pragma unroll
      for (int hh = 0; hh < 4; ++hh) {
        const float lc = lcS[hh][row];
        if (lc > 0.f) {
          const int cb = 4 * mm;
          float a = Plds[hh][row][cb] + Plds[hh][row][cb + 1] + Plds[hh][row][cb + 2];
          if (cb >= 1)       a += 0.5f * Plds[hh][row][cb - 1];
          if (cb + 3 < SCMP) a += 0.5f * Plds[hh][row][cb + 3];
          psl += a / lc;
        }
      }
      const bool causal = (mm <= bmax);
      const bool forced = (mm == 0) || (mm == bmax);
      lgS[row][mm] = causal ? (psl + (forced ? 1e6f : 0.f)) : -1e9f;
    }
    __syncthreads();
    {
      const int row = tid >> 4, mm = tid & 15;
      const float my = lgS[row][mm];
      int rank = 0;
#pragma unroll
      for (int m2 = 0; m2 < 16; ++m2) {
        const float v = lgS[row][m2];
        if (v > my || (v == my && m2 < mm)) ++rank;
      }
      if (rank < NSELK && mm <= bmax) atomicOr(&selmaskS[row], 1u << mm);
    }
    __syncthreads();
    if (tid == 0) {
      unsigned u = 0;
      for (int r = 0; r < QBLK; ++r) u |= selmaskS[r];
      int n = 0;
      for (int b = 0; b < 16; ++b) if ((u >> b) & 1u) selListS[n++] = b;
      nselS = n;
    }
    __syncthreads();
    const int nt = nselS;   // >= 1

    // ---- sel branch: pipelined over selected-block list ----
    ARESET();
    {
      const int b0 = selListS[0];
      stage_tile(kselb + (size_t)b0 * 64 * 256 + g * 64, 256,
                 vselT + (size_t)g * 64 * 1024 + b0 * 64, 1024,
                 Klds[0], Vlds[0], tid);
      __syncthreads();
      for (int i = 0; i < nt; ++i) {
        if (i + 1 < nt) {
          const int bn = selListS[i + 1];
          stage_tile(kselb + (size_t)bn * 64 * 256 + g * 64, 256,
                     vselT + (size_t)g * 64 * 1024 + bn * 64, 1024,
                     Klds[(i + 1) & 1], Vlds[(i + 1) & 1], tid);
        }
        attn_compute<1>(selListS[i], s0, l, aq0, aq1, ps, Oa,
                        Klds[i & 1], Vlds[i & 1], Plds[w], selmaskS);
        __syncthreads();
      }
    }
    REDUCE_LS();
    AFINAL(1);

#pragma unroll
    for (int f = 0; f < 4; ++f)
#pragma unroll
      for (int r = 0; r < 4; ++r) {
        const int sr = s0 + kg * 4 + r;
        Ocs[(size_t)(sr * 16 + g * 4 + w) * 64 + 16 * f + lr] = Ot[f][r];
      }
  } else {
    // ---- win branch ----
    ARESET();
    const int blo = (s0 >= (WWIN - 1)) ? ((s0 - (WWIN - 1)) >> 6) : 0;
    const int nt = bmax - blo + 1;
    stage_tile(kwinb + (size_t)blo * 64 * 256 + g * 64, 256,
               vwinT + (size_t)g * 64 * 1024 + blo * 64, 1024,
               Klds[0], Vlds[0], tid);
    __syncthreads();
    for (int i = 0; i < nt; ++i) {
      if (i + 1 < nt) {
        const int bn = blo + i + 1;
        stage_tile(kwinb + (size_t)bn * 64 * 256 + g * 64, 256,
                   vwinT + (size_t)g * 64 * 1024 + bn * 64, 1024,
                   Klds[(i + 1) & 1], Vlds[(i + 1) & 1], tid);
      }
      attn_compute<2>(blo + i, s0, l, aq0, aq1, ps, Oa,
                      Klds[i & 1], Vlds[i & 1], Plds[w], selmaskS);
      __syncthreads();
    }
    REDUCE_LS();
    AFINAL(2);

#pragma unroll
    for (int f = 0; f < 4; ++f)
#pragma unroll
      for (int r = 0; r < 4; ++r) {
        const int sr = s0 + kg * 4 + r;
        Owin[(size_t)(sr * 16 + g * 4 + w) * 64 + 16 * f + lr] = Ot[f][r];
      }
  }
#undef ARESET
#undef REDUCE_LS
#undef AFINAL
}

// ---------------- launch ----------------
extern "C" void kernel_launch(void* const* d_in, const int* in_sizes, int n_in,
                              void* d_out, int out_size, void* d_ws, size_t ws_size,
                              hipStream_t stream) {
  const float* x      = (const float*)d_in[0];
  const float* wq     = (const float*)d_in[1];
  const float* wk_sel = (const float*)d_in[2];
  const float* wv_sel = (const float*)d_in[3];
  const float* wk_win = (const float*)d_in[4];
  const float* wv_win = (const float*)d_in[5];
  const float* wk_cmp = (const float*)d_in[6];
  const float* wv_cmp = (const float*)d_in[7];
  const float* w_out  = (const float*)d_in[8];
  const float* g1w    = (const float*)d_in[9];
  const float* g1b    = (const float*)d_in[10];
  const float* g2w    = (const float*)d_in[11];
  const float* g2b    = (const float*)d_in[12];

  float* ws = (float*)d_ws;
  float* q     = ws;                         // 1,048,576 f32 (raw q proj)
  float* kv    = q + 1048576;                // 6 x 262,144 f32
  float* ksel  = kv;
  float* vsel  = kv + 1 * 262144;
  float* kwin  = kv + 2 * 262144;
  float* vwin  = kv + 3 * 262144;
  float* kcmp  = kv + 4 * 262144;
  float* vcmp  = kv + 5 * 262144;
  float* gts   = kv + 6 * 262144;            // 12,288 f32
  float* Obuf  = gts + 12288;                // 1,048,576 f32 (Ocs; first 64K = sincos tab before attn)
  float* Owin  = kv;                         // alias: ksel..vwin f32 dead after prep/transpose
  float2* tab  = (float2*)Obuf;              // [1024][32] cs/sn — consumed by pool before attn

  unsigned short* xb     = (unsigned short*)(Obuf + 1048576);
  unsigned short* wqb    = xb + 1048576;
  unsigned short* kvwb   = wqb + 1048576;    // 6 x 262,144
  unsigned short* w_outb = kvwb + 6 * 262144;
  unsigned short* q_b    = w_outb + 1048576; // 1,048,576
  unsigned short* kselb  = q_b + 1048576;    // 262,144
  unsigned short* kwinb  = kselb + 262144;
  unsigned short* vselT  = kwinb + 262144;   // 262,144 (transposed)
  unsigned short* vwinT  = vselT + 262144;
  unsigned short* KcB    = vwinT + 262144;   // 16,384
  unsigned short* VcTB   = KcB + 16384;      // 16,384

  // inputs -> bf16
  ConvJobs j1 = {};
  j1.cnt = 9;
  j1.src[0] = x;      j1.dst[0] = (unsigned*)xb;                j1.n4[0] = 262144;
  j1.src[1] = wq;     j1.dst[1] = (unsigned*)wqb;               j1.n4[1] = 262144;
  j1.src[2] = wk_sel; j1.dst[2] = (unsigned*)(kvwb + 0*262144); j1.n4[2] = 65536;
  j1.src[3] = wv_sel; j1.dst[3] = (unsigned*)(kvwb + 1*262144); j1.n4[3] = 65536;
  j1.src[4] = wk_win; j1.dst[4] = (unsigned*)(kvwb + 2*262144); j1.n4[4] = 65536;
  j1.src[5] = wv_win; j1.dst[5] = (unsigned*)(kvwb + 3*262144); j1.n4[5] = 65536;
  j1.src[6] = wk_cmp; j1.dst[6] = (unsigned*)(kvwb + 4*262144); j1.n4[6] = 65536;
  j1.src[7] = wv_cmp; j1.dst[7] = (unsigned*)(kvwb + 5*262144); j1.n4[7] = 65536;
  j1.src[8] = w_out;  j1.dst[8] = (unsigned*)w_outb;            j1.n4[8] = 262144;
  conv_f32_bf16<<<1024, 256, 0, stream>>>(j1);

  // projections
  gemm_bf16<<<dim3(16, 16), 256, 0, stream>>>(xb, wqb, q, 1024, 1024);
  W6 p6 = {{ kvwb + 0*262144, kvwb + 1*262144, kvwb + 2*262144,
             kvwb + 3*262144, kvwb + 4*262144, kvwb + 5*262144 }};
  gemm_bf16_kv6<<<dim3(4, 16, 6), 256, 0, stream>>>(xb, p6, kv);

  // fused rope + gates + bf16 conversions + sincos table
  prep_kernel<<<1024, 256, 0, stream>>>(q, ksel, kwin, g1w, g1b, g2w, g2b,
                                        q_b, kselb, kwinb, gts, tab);

  // pooled cmp K/V (rope inline) -> bf16
  pool_kernel<<<dim3(64, 4), 64, 0, stream>>>(kcmp, vcmp, tab, KcB, VcTB);

  // v -> transposed bf16
  transpose_v<<<dim3(32, 8, 2), 256, 0, stream>>>(vsel, vwin, vselT, vwinT);

  // fused MFMA NSA attention (z=0: cmp+sel, z=1: win)
  attn_mfma_kernel<<<dim3(64, 4, 2), 256, 0, stream>>>(
      q_b, kselb, vselT, kwinb, vwinT, KcB, VcTB, gts, Obuf, Owin);

  // combine + output projection
  conv_add_bf16<<<1024, 256, 0, stream>>>(Obuf, Owin, (uint2*)xb);
  gemm_bf16<<<dim3(16, 16), 256, 0, stream>>>(xb, w_outb, (float*)d_out, 1024, 1024);
}

// Round 6
// 112.706 us; speedup vs baseline: 4.9049x; 1.0862x over previous
//
#include <hip/hip_runtime.h>
#include <math.h>

// ---------------- problem constants ----------------
#define SLEN   1024
#define NGRP   4
#define NHEAD  16
#define HPGRP  4
#define DKV    64
#define SCMP   63     // (1024-32)/16+1
#define NBLK   16
#define NSELK  8
#define WWIN   512
#define SCALEF 0.125f // 1/sqrt(64)
#define QBLK   16
#define EXPOFF 8.0f   // fixed softmax offset: exp(sc-8); scores bounded << 80
#define CSTR   2560   // fused QKV GEMM output row stride

typedef __attribute__((ext_vector_type(4))) float f32x4;
typedef __attribute__((ext_vector_type(8))) short bf16x8;

// ---------------- f32 -> bf16 (RNE) helpers ----------------
__device__ __forceinline__ unsigned short f2bf(float f) {
  unsigned u = __float_as_uint(f);
  u += 0x7FFFu + ((u >> 16) & 1u);
  return (unsigned short)(u >> 16);
}
__device__ __forceinline__ unsigned pack2(float a, float b) {
  return (unsigned)f2bf(a) | ((unsigned)f2bf(b) << 16);
}
__device__ __forceinline__ bf16x8 pack8(float4 a, float4 b) {
  union { bf16x8 v; unsigned u[4]; } u;
  u.u[0] = pack2(a.x, a.y); u.u[1] = pack2(a.z, a.w);
  u.u[2] = pack2(b.x, b.y); u.u[3] = pack2(b.z, b.w);
  return u.v;
}

struct ConvJobs {
  const float* src[9];
  unsigned* dst[9];
  int n4[9];
  int cnt;
};

__global__ __launch_bounds__(256) void conv_f32_bf16(ConvJobs jb) {
  const int stride = gridDim.x * blockDim.x;
  for (int t = 0; t < jb.cnt; ++t) {
    const float4* s = (const float4*)jb.src[t];
    uint2* d = (uint2*)jb.dst[t];
    const int n4 = jb.n4[t];
    for (int i = blockIdx.x * blockDim.x + threadIdx.x; i < n4; i += stride) {
      const float4 v = s[i];
      uint2 o;
      o.x = pack2(v.x, v.y);
      o.y = pack2(v.z, v.w);
      d[i] = o;
    }
  }
}

// sum two f32 buffers -> bf16
__global__ __launch_bounds__(256) void conv_add_bf16(
    const float* __restrict__ a, const float* __restrict__ b, uint2* __restrict__ d)
{
  const int i = blockIdx.x * 256 + threadIdx.x;
  const float4 va = ((const float4*)a)[i];
  const float4 vb = ((const float4*)b)[i];
  uint2 o;
  o.x = pack2(va.x + vb.x, va.y + vb.y);
  o.y = pack2(va.z + vb.z, va.w + vb.w);
  d[i] = o;
}

// ---------------- async global->LDS 16B ----------------
__device__ __forceinline__ void gload_lds16(const unsigned short* g, unsigned short* l) {
  __builtin_amdgcn_global_load_lds(
      (const __attribute__((address_space(1))) void*)g,
      (__attribute__((address_space(3))) void*)l, 16, 0, 0);
}

// ---------------- bf16 MFMA GEMM: C[M][N] = A[M][K] @ W[N][K]^T ----------------
__device__ __forceinline__ void gemm_mfma_body(
    const unsigned short* __restrict__ A, const unsigned short* __restrict__ W,
    float* __restrict__ C, int N, int K, int bm, int bn, int tid)
{
  __shared__ unsigned short As[3][2048];
  __shared__ unsigned short Bs[3][2048];
  const int lane = tid & 63;
  const int wave = tid >> 6;
  const int wr = wave >> 1, wc = wave & 1;

  const int sub = tid >> 6;
  const int kh  = (tid >> 4) & 3;
  const int row = tid & 15;
  const unsigned short* aSrc = A + (size_t)(bm + sub * 16 + row) * K + kh * 8;
  const unsigned short* bSrc = W + (size_t)(bn + sub * 16 + row) * K + kh * 8;
  const int slot = tid * 8;

  f32x4 acc[2][2];
#pragma unroll
  for (int m = 0; m < 2; ++m)
#pragma unroll
    for (int n = 0; n < 2; ++n) acc[m][n] = (f32x4){0.f, 0.f, 0.f, 0.f};

  const int NIT = K >> 5;
  gload_lds16(aSrc + 0,  &As[0][slot]);
  gload_lds16(bSrc + 0,  &Bs[0][slot]);
  gload_lds16(aSrc + 32, &As[1][slot]);
  gload_lds16(bSrc + 32, &Bs[1][slot]);

  for (int i = 0; i < NIT; ++i) {
    __builtin_amdgcn_sched_barrier(0);
    if (i + 1 < NIT) asm volatile("s_waitcnt vmcnt(2)" ::: "memory");
    else             asm volatile("s_waitcnt vmcnt(0)" ::: "memory");
    __builtin_amdgcn_s_barrier();
    __builtin_amdgcn_sched_barrier(0);
    if (i + 2 < NIT) {
      const int nb = (i + 2) % 3;
      gload_lds16(aSrc + (i + 2) * 32, &As[nb][slot]);
      gload_lds16(bSrc + (i + 2) * 32, &Bs[nb][slot]);
    }
    const int cur = i % 3;
    const bf16x8 a0 = *(const bf16x8*)(&As[cur][(wr * 2 + 0) * 512 + lane * 8]);
    const bf16x8 a1 = *(const bf16x8*)(&As[cur][(wr * 2 + 1) * 512 + lane * 8]);
    const bf16x8 b0 = *(const bf16x8*)(&Bs[cur][(wc * 2 + 0) * 512 + lane * 8]);
    const bf16x8 b1 = *(const bf16x8*)(&Bs[cur][(wc * 2 + 1) * 512 + lane * 8]);
    acc[0][0] = __builtin_amdgcn_mfma_f32_16x16x32_bf16(a0, b0, acc[0][0], 0, 0, 0);
    acc[0][1] = __builtin_amdgcn_mfma_f32_16x16x32_bf16(a0, b1, acc[0][1], 0, 0, 0);
    acc[1][0] = __builtin_amdgcn_mfma_f32_16x16x32_bf16(a1, b0, acc[1][0], 0, 0, 0);
    acc[1][1] = __builtin_amdgcn_mfma_f32_16x16x32_bf16(a1, b1, acc[1][1], 0, 0, 0);
  }

  const int cr = (lane >> 4) * 4;
  const int cc = lane & 15;
#pragma unroll
  for (int m = 0; m < 2; ++m)
#pragma unroll
    for (int n = 0; n < 2; ++n) {
      float* cp = C + (size_t)(bm + wr * 32 + m * 16 + cr) * N + (bn + wc * 32 + n * 16 + cc);
#pragma unroll
      for (int r = 0; r < 4; ++r) cp[(size_t)r * N] = acc[m][n][r];
    }
}

__global__ __launch_bounds__(256) void gemm_bf16(
    const unsigned short* __restrict__ A, const unsigned short* __restrict__ W,
    float* __restrict__ C, int N, int K)
{
  gemm_mfma_body(A, W, C, N, K, blockIdx.y * 64, blockIdx.x * 64, threadIdx.x);
}

// ---------------- merged mid kernel: prep(1024) | transpose(512) | pool(64) ----------------
// C = [1024][2560] f32: q 0-1023 | ksel 1024 | vsel 1280 | kwin 1536 | vwin 1792 | kcmp 2048 | vcmp 2304
__global__ __launch_bounds__(256) void mid_kernel(
    const float* __restrict__ C,
    const float* __restrict__ g1w, const float* __restrict__ g1b,
    const float* __restrict__ g2w, const float* __restrict__ g2b,
    unsigned short* __restrict__ q_b,
    unsigned short* __restrict__ kselb, unsigned short* __restrict__ kwinb,
    float* __restrict__ gates,
    unsigned short* __restrict__ vselT, unsigned short* __restrict__ vwinT,
    unsigned short* __restrict__ KcB, unsigned short* __restrict__ VcTB)
{
  const int b = blockIdx.x;
  const int t = threadIdx.x;

  __shared__ float csS[32], snS[32];
  __shared__ float qs[1024];
  __shared__ float qgS[4][64];
  __shared__ float h1S[4][32];
  __shared__ float glS[4][3];
  __shared__ float tile[32][33];
  __shared__ float csP[32][32], snP[32][32];

  if (b < 1024) {
    // ================= prep: rope q/ksel/kwin + q_b + gates =================
    const int s = b;
    if (t < 32) {
      const float inv = powf(10000.f, -(float)t * (1.f / 32.f));
      float sn, cs;
      sincosf((float)s * inv, &sn, &cs);
      csS[t] = cs; snS[t] = sn;
    }
    __syncthreads();
    {
      const int ht = t >> 4;
      const float* qr = C + (size_t)s * CSTR + ht * 64;
#pragma unroll
      for (int i = 0; i < 2; ++i) {
        const int dd = (t & 15) * 2 + i;
        const float x1 = qr[dd], x2 = qr[dd + 32];
        qs[ht * 64 + dd]      = x1 * csS[dd] - x2 * snS[dd];
        qs[ht * 64 + dd + 32] = x1 * snS[dd] + x2 * csS[dd];
      }
    }
    {
      const int which = t >> 7;
      const int g = (t >> 5) & 3, dd = t & 31;
      const float* src = C + (size_t)s * CSTR + (which ? 1536 : 1024) + g * 64;
      unsigned short* dst = (which ? kwinb : kselb) + (size_t)s * 256 + g * 64;
      const float x1 = src[dd], x2 = src[dd + 32];
      dst[dd]      = f2bf(x1 * csS[dd] - x2 * snS[dd]);
      dst[dd + 32] = f2bf(x1 * snS[dd] + x2 * csS[dd]);
    }
    __syncthreads();
    {
      uint2 o;
      o.x = pack2(qs[t * 4 + 0], qs[t * 4 + 1]);
      o.y = pack2(qs[t * 4 + 2], qs[t * 4 + 3]);
      *(uint2*)(q_b + (size_t)s * 1024 + t * 4) = o;
    }
    {
      const int g = t >> 6, d = t & 63;
      qgS[g][d] = (qs[g * 256 + d] + qs[g * 256 + 64 + d] +
                   qs[g * 256 + 128 + d] + qs[g * 256 + 192 + d]) * 0.25f;
    }
    __syncthreads();
    if (t < 128) {
      const int g = t >> 5, j = t & 31;
      float a = g1b[j];
      for (int d = 0; d < 64; ++d) a += qgS[g][d] * g1w[j * 64 + d];
      h1S[g][j] = a / (1.f + expf(-a));
    }
    __syncthreads();
    if (t < 16) {
      const int g = t >> 2, rr = t & 3;
      if (rr < 3) {
        float a = g2b[rr];
        for (int j = 0; j < 32; ++j) a += h1S[g][j] * g2w[rr * 32 + j];
        glS[g][rr] = a;
      }
    }
    __syncthreads();
    if (t < 4) {
      const int g = t;
      const float gl0 = glS[g][0], gl1 = glS[g][1], gl2 = glS[g][2];
      const float m1 = fmaxf(gl0, fmaxf(gl1, gl2));
      const float e0 = expf(gl0 - m1), e1 = expf(gl1 - m1), e2 = expf(gl2 - m1);
      const float inv = 1.f / (e0 + e1 + e2);
      float p0 = e0 * inv, p1 = e1 * inv, p2 = e2 * inv;
      int am = 0; float best = gl0;
      if (gl1 > best) { best = gl1; am = 1; }
      if (gl2 > best) { best = gl2; am = 2; }
      float second = -INFINITY;
      if (am != 0) second = fmaxf(second, gl0);
      if (am != 1) second = fmaxf(second, gl1);
      if (am != 2) second = fmaxf(second, gl2);
      if (best - second > 50.f) {
        p0 = (am == 0) ? 1.f : 0.f; p1 = (am == 1) ? 1.f : 0.f; p2 = (am == 2) ? 1.f : 0.f;
      }
      float* o = gates + (size_t)(s * 4 + g) * 3;
      o[0] = p0; o[1] = p1; o[2] = p2;
    }
  } else if (b < 1536) {
    // ================= transpose vsel/vwin -> [256][1024] bf16 =================
    const int idx = b - 1024;
    const int tr = (idx & 31) * 32, tc = ((idx >> 5) & 7) * 32;
    const int z = idx >> 8;
    const int off = z ? 1792 : 1280;
    unsigned short* dst = z ? vwinT : vselT;
    const int r = t >> 5, c = t & 31;
#pragma unroll
    for (int i = 0; i < 4; ++i)
      tile[r + i * 8][c] = C[(size_t)(tr + r + i * 8) * CSTR + off + tc + c];
    __syncthreads();
#pragma unroll
    for (int i = 0; i < 4; ++i)
      dst[(size_t)(tc + r + i * 8) * 1024 + tr + c] = f2bf(tile[c][r + i * 8]);
  } else {
    // ================= pool: cmp K (rope inline) / V mean over 32 tokens =================
    const int c = b - 1536;          // 0..63 (63 = zero pad)
    const int g = t >> 6, d = t & 63;
    // block-local sincos for positions c*16 .. c*16+31
#pragma unroll
    for (int qq = 0; qq < 4; ++qq) {
      const int idx = t * 4 + qq;
      const int j = idx >> 5, dd = idx & 31;
      const float inv = powf(10000.f, -(float)dd * (1.f / 32.f));
      float sn, cs;
      sincosf((float)(c * 16 + j) * inv, &sn, &cs);
      csP[j][dd] = cs; snP[j][dd] = sn;
    }
    __syncthreads();
    float ak = 0.f, av = 0.f;
    if (c < SCMP) {
      const int d2 = d & 31;
      for (int j = 0; j < 32; ++j) {
        const int pos = c * 16 + j;
        const float k1 = C[(size_t)pos * CSTR + 2048 + g * 64 + d2];
        const float k2 = C[(size_t)pos * CSTR + 2048 + g * 64 + d2 + 32];
        ak += (d < 32) ? (k1 * csP[j][d2] - k2 * snP[j][d2])
                       : (k1 * snP[j][d2] + k2 * csP[j][d2]);
        av += C[(size_t)pos * CSTR + 2304 + g * 64 + d];
      }
      ak *= (1.f / 32.f); av *= (1.f / 32.f);
    }
    KcB[(size_t)(g * 64 + c) * 64 + d] = f2bf(ak);
    VcTB[(size_t)(g * 64 + d) * 64 + c] = f2bf(av);
  }
}

// ---------------- MFMA NSA attention ----------------
// grid = (64 qtiles of 16 rows, 4 groups, 2): z=0 -> cmp+sel (Ocs), z=1 -> win (Owin).
// 4 waves = 4 heads. Fixed-offset softmax, deferred denominator.
// Tile loop: 3-buffer LDS, 1-ahead prefetch, counted vmcnt(4), one raw s_barrier/tile.
__device__ __forceinline__ void stage_tile(
    const unsigned short* kbase, int krow,
    const unsigned short* vbase, int vrow,
    unsigned short* Kb, unsigned short* Vb, int tid)
{
#pragma unroll
  for (int i = 0; i < 2; ++i) {
    const int t2 = tid + i * 256;
    const int sf = t2 >> 7, sks = (t2 >> 6) & 1, skh = (t2 >> 4) & 3, stk = t2 & 15;
    gload_lds16(kbase + (size_t)(16 * sf + stk) * krow + sks * 32 + skh * 8, Kb + t2 * 8);
    gload_lds16(vbase + (size_t)(16 * sf + stk) * vrow + sks * 32 + skh * 8, Vb + t2 * 8);
  }
}

// BR: 0=cmp, 1=sel (per-row 16-bit block mask), 2=win (sliding window)
template<int BR>
__device__ __forceinline__ void attn_compute(
    int b, int s0, int l,
    bf16x8 aq0, bf16x8 aq1,
    float (&ps)[4], f32x4 (&Oa)[4],
    const unsigned short* Klds, const unsigned short* Vlds,
    float (*Pw)[68], const unsigned* selmaskS)
{
  const int kg = l >> 4, lr = l & 15;
  f32x4 sc[4];
  __builtin_amdgcn_s_setprio(1);
#pragma unroll
  for (int f = 0; f < 4; ++f) {
    sc[f] = (f32x4){0.f, 0.f, 0.f, 0.f};
    sc[f] = __builtin_amdgcn_mfma_f32_16x16x32_bf16(
        aq0, *(const bf16x8*)(Klds + (f * 2 + 0) * 512 + l * 8), sc[f], 0, 0, 0);
    sc[f] = __builtin_amdgcn_mfma_f32_16x16x32_bf16(
        aq1, *(const bf16x8*)(Klds + (f * 2 + 1) * 512 + l * 8), sc[f], 0, 0, 0);
  }
  __builtin_amdgcn_s_setprio(0);

#pragma unroll
  for (int r = 0; r < 4; ++r) {
    const int lrow = kg * 4 + r;
    const int sr = s0 + lrow;
#pragma unroll
    for (int f = 0; f < 4; ++f) {
      const int tok = b * 64 + 16 * f + lr;
      bool ok;
      if (BR == 0)      ok = (tok < SCMP) && (tok * 16 + 31 <= sr);
      else if (BR == 1) ok = ((selmaskS[lrow] >> b) & 1u) && (tok <= sr);
      else              ok = (tok <= sr) && (tok > sr - WWIN);
      const float p = ok ? __expf(sc[f][r] * SCALEF - EXPOFF) : 0.f;
      Pw[lrow][16 * f + lr] = p;
      ps[r] += p;
    }
  }
  asm volatile("s_waitcnt lgkmcnt(0)" ::: "memory");  // wave's P writes visible
#pragma unroll
  for (int ks = 0; ks < 2; ++ks) {
    const float4 pa0 = *(const float4*)&Pw[lr][ks * 32 + kg * 8];
    const float4 pa1 = *(const float4*)&Pw[lr][ks * 32 + kg * 8 + 4];
    const bf16x8 pa = pack8(pa0, pa1);
    __builtin_amdgcn_s_setprio(1);
#pragma unroll
    for (int f = 0; f < 4; ++f)
      Oa[f] = __builtin_amdgcn_mfma_f32_16x16x32_bf16(
          pa, *(const bf16x8*)(Vlds + (f * 2 + ks) * 512 + l * 8), Oa[f], 0, 0, 0);
    __builtin_amdgcn_s_setprio(0);
  }
}

// pipelined barrier helper: counted vmcnt keeps next tile's loads in flight
#define TILE_SYNC(more) do { \
    __builtin_amdgcn_sched_barrier(0); \
    if (more) asm volatile("s_waitcnt vmcnt(4)" ::: "memory"); \
    else      asm volatile("s_waitcnt vmcnt(0)" ::: "memory"); \
    __builtin_amdgcn_sched_barrier(0); \
    __builtin_amdgcn_s_barrier(); \
    __builtin_amdgcn_sched_barrier(0); \
  } while (0)

__global__ __launch_bounds__(256) void attn_mfma_kernel(
    const unsigned short* __restrict__ qb,     // [S][16][64] bf16 (roped)
    const unsigned short* __restrict__ kselb,  // [S][256] bf16 (roped)
    const unsigned short* __restrict__ vselT,  // [256][S] bf16
    const unsigned short* __restrict__ kwinb,
    const unsigned short* __restrict__ vwinT,
    const unsigned short* __restrict__ KcB,    // [g*64+c][64] bf16
    const unsigned short* __restrict__ VcTB,   // [g*64+d][64] bf16
    const float* __restrict__ gates,           // [S][4][3]
    float* __restrict__ Ocs, float* __restrict__ Owin)
{
  const int qt = blockIdx.x;
  const int g  = blockIdx.y;
  const int z  = blockIdx.z;
  const int s0 = qt * QBLK;
  const int tid = threadIdx.x;
  const int w = tid >> 6, l = tid & 63;    // w = head
  const int kg = l >> 4, lr = l & 15;
  const int bmax = s0 >> 6;

  __shared__ unsigned short Klds[3][4096];
  __shared__ unsigned short Vlds[3][4096];
  __shared__ float Plds[4][16][68];
  __shared__ float lgS[QBLK][16];
  __shared__ float lcS[4][16];
  __shared__ unsigned selmaskS[QBLK];
  __shared__ int selListS[16];
  __shared__ int nselS;

  if (tid < QBLK) selmaskS[tid] = 0u;

  const int sq = s0 + lr;
  const unsigned short* qrow = qb + (size_t)(sq * 16 + g * 4 + w) * 64;
  const bf16x8 aq0 = *(const bf16x8*)(qrow + kg * 8);
  const bf16x8 aq1 = *(const bf16x8*)(qrow + 32 + kg * 8);

  float gv[3][4];
#pragma unroll
  for (int r = 0; r < 4; ++r) {
    const int sr = s0 + kg * 4 + r;
    const float* gp = gates + (size_t)(sr * 4 + g) * 3;
    gv[0][r] = gp[0]; gv[1][r] = gp[1]; gv[2][r] = gp[2];
  }

  f32x4 Ot[4];
#pragma unroll
  for (int f = 0; f < 4; ++f) Ot[f] = (f32x4){0.f, 0.f, 0.f, 0.f};

  float ps[4], ls[4];
  f32x4 Oa[4];

#define ARESET() do { \
    _Pragma("unroll") for (int r = 0; r < 4; ++r) ps[r] = 0.f; \
    _Pragma("unroll") for (int f = 0; f < 4; ++f) Oa[f] = (f32x4){0.f,0.f,0.f,0.f}; \
  } while (0)
#define REDUCE_LS() do { \
    _Pragma("unroll") for (int r = 0; r < 4; ++r) { \
      ls[r] = ps[r]; \
      ls[r] += __shfl_xor(ls[r], 1); ls[r] += __shfl_xor(ls[r], 2); \
      ls[r] += __shfl_xor(ls[r], 4); ls[r] += __shfl_xor(ls[r], 8); } \
  } while (0)
#define AFINAL(bi) do { \
    _Pragma("unroll") for (int f = 0; f < 4; ++f) \
    _Pragma("unroll") for (int r = 0; r < 4; ++r) \
      Ot[f][r] += gv[bi][r] * ((ls[r] > 0.f) ? (Oa[f][r] / ls[r]) : 0.f); \
  } while (0)

  if (z == 0) {
    // ---- cmp branch (single tile) ----
    ARESET();
    stage_tile(KcB + (size_t)g * 64 * 64, 64, VcTB + (size_t)g * 64 * 64, 64,
               Klds[0], Vlds[0], tid);
    TILE_SYNC(0);
    attn_compute<0>(0, s0, l, aq0, aq1, ps, Oa, Klds[0], Vlds[0], Plds[w], selmaskS);
    REDUCE_LS();
    if ((l & 15) == 0) {
#pragma unroll
      for (int r = 0; r < 4; ++r) lcS[w][kg * 4 + r] = ls[r];
    }
    AFINAL(0);
    __syncthreads();   // cmp P + lcS visible block-wide

    // ---- selection: p_slc (M_MAP inline), lg, top-8 ----
    {
      const int row = tid >> 4, mm = tid & 15;
      float psl = 0.f;
#pragma unroll
      for (int hh = 0; hh < 4; ++hh) {
        const float lc = lcS[hh][row];
        if (lc > 0.f) {
          const int cb = 4 * mm;
          float a = Plds[hh][row][cb] + Plds[hh][row][cb + 1] + Plds[hh][row][cb + 2];
          if (cb >= 1)       a += 0.5f * Plds[hh][row][cb - 1];
          if (cb + 3 < SCMP) a += 0.5f * Plds[hh][row][cb + 3];
          psl += a / lc;
        }
      }
      const bool causal = (mm <= bmax);
      const bool forced = (mm == 0) || (mm == bmax);
      lgS[row][mm] = causal ? (psl + (forced ? 1e6f : 0.f)) : -1e9f;
    }
    __syncthreads();
    {
      const int row = tid >> 4, mm = tid & 15;
      const float my = lgS[row][mm];
      int rank = 0;
#pragma unroll
      for (int m2 = 0; m2 < 16; ++m2) {
        const float v = lgS[row][m2];
        if (v > my || (v == my && m2 < mm)) ++rank;
      }
      if (rank < NSELK && mm <= bmax) atomicOr(&selmaskS[row], 1u << mm);
    }
    __syncthreads();
    if (tid == 0) {
      unsigned u = 0;
      for (int r = 0; r < QBLK; ++r) u |= selmaskS[r];
      int n = 0;
      for (int b = 0; b < 16; ++b) if ((u >> b) & 1u) selListS[n++] = b;
      nselS = n;
    }
    __syncthreads();
    const int nt = nselS;   // >= 1

    // ---- sel branch: 3-buffer counted-vmcnt pipeline ----
    ARESET();
    {
      const int b0 = selListS[0];
      stage_tile(kselb + (size_t)b0 * 64 * 256 + g * 64, 256,
                 vselT + (size_t)g * 64 * 1024 + b0 * 64, 1024,
                 Klds[0], Vlds[0], tid);
      for (int i = 0; i < nt; ++i) {
        if (i + 1 < nt) {
          const int bn = selListS[i + 1];
          const int nb = (i + 1) % 3;
          stage_tile(kselb + (size_t)bn * 64 * 256 + g * 64, 256,
                     vselT + (size_t)g * 64 * 1024 + bn * 64, 1024,
                     Klds[nb], Vlds[nb], tid);
        }
        TILE_SYNC(i + 1 < nt);
        attn_compute<1>(selListS[i], s0, l, aq0, aq1, ps, Oa,
                        Klds[i % 3], Vlds[i % 3], Plds[w], selmaskS);
        __builtin_amdgcn_sched_barrier(0);
      }
    }
    REDUCE_LS();
    AFINAL(1);

#pragma unroll
    for (int f = 0; f < 4; ++f)
#pragma unroll
      for (int r = 0; r < 4; ++r) {
        const int sr = s0 + kg * 4 + r;
        Ocs[(size_t)(sr * 16 + g * 4 + w) * 64 + 16 * f + lr] = Ot[f][r];
      }
  } else {
    // ---- win branch: 3-buffer counted-vmcnt pipeline ----
    ARESET();
    const int blo = (s0 >= (WWIN - 1)) ? ((s0 - (WWIN - 1)) >> 6) : 0;
    const int nt = bmax - blo + 1;
    stage_tile(kwinb + (size_t)blo * 64 * 256 + g * 64, 256,
               vwinT + (size_t)g * 64 * 1024 + blo * 64, 1024,
               Klds[0], Vlds[0], tid);
    for (int i = 0; i < nt; ++i) {
      if (i + 1 < nt) {
        const int bn = blo + i + 1;
        const int nb = (i + 1) % 3;
        stage_tile(kwinb + (size_t)bn * 64 * 256 + g * 64, 256,
                   vwinT + (size_t)g * 64 * 1024 + bn * 64, 1024,
                   Klds[nb], Vlds[nb], tid);
      }
      TILE_SYNC(i + 1 < nt);
      attn_compute<2>(blo + i, s0, l, aq0, aq1, ps, Oa,
                      Klds[i % 3], Vlds[i % 3], Plds[w], selmaskS);
      __builtin_amdgcn_sched_barrier(0);
    }
    REDUCE_LS();
    AFINAL(2);

#pragma unroll
    for (int f = 0; f < 4; ++f)
#pragma unroll
      for (int r = 0; r < 4; ++r) {
        const int sr = s0 + kg * 4 + r;
        Owin[(size_t)(sr * 16 + g * 4 + w) * 64 + 16 * f + lr] = Ot[f][r];
      }
  }
#undef ARESET
#undef REDUCE_LS
#undef AFINAL
}

// ---------------- launch ----------------
extern "C" void kernel_launch(void* const* d_in, const int* in_sizes, int n_in,
                              void* d_out, int out_size, void* d_ws, size_t ws_size,
                              hipStream_t stream) {
  const float* x      = (const float*)d_in[0];
  const float* wq     = (const float*)d_in[1];
  const float* wk_sel = (const float*)d_in[2];
  const float* wv_sel = (const float*)d_in[3];
  const float* wk_win = (const float*)d_in[4];
  const float* wv_win = (const float*)d_in[5];
  const float* wk_cmp = (const float*)d_in[6];
  const float* wv_cmp = (const float*)d_in[7];
  const float* w_out  = (const float*)d_in[8];
  const float* g1w    = (const float*)d_in[9];
  const float* g1b    = (const float*)d_in[10];
  const float* g2w    = (const float*)d_in[11];
  const float* g2b    = (const float*)d_in[12];

  float* ws = (float*)d_ws;
  float* Cq    = ws;                          // 1024*2560 = 2,621,440 f32
  float* gts   = Cq + 2621440;                // 12,288
  float* Ocs   = gts + 12288;                 // 1,048,576
  float* Owin  = Ocs + 1048576;               // 1,048,576

  unsigned short* xb     = (unsigned short*)(Owin + 1048576);  // 1,048,576
  unsigned short* wqkvb  = xb + 1048576;      // 2560*1024 = 2,621,440 (wq | 6 kv weights)
  unsigned short* w_outb = wqkvb + 2621440;   // 1,048,576
  unsigned short* q_b    = w_outb + 1048576;  // 1,048,576
  unsigned short* kselb  = q_b + 1048576;     // 262,144
  unsigned short* kwinb  = kselb + 262144;    // 262,144
  unsigned short* vselT  = kwinb + 262144;    // 262,144
  unsigned short* vwinT  = vselT + 262144;    // 262,144
  unsigned short* KcB    = vwinT + 262144;    // 16,384
  unsigned short* VcTB   = KcB + 16384;       // 16,384

  // inputs -> bf16 (weights laid out contiguously: wq rows 0-1023, then 6 kv weights)
  ConvJobs j1 = {};
  j1.cnt = 9;
  j1.src[0] = x;      j1.dst[0] = (unsigned*)xb;                        j1.n4[0] = 262144;
  j1.src[1] = wq;     j1.dst[1] = (unsigned*)wqkvb;                     j1.n4[1] = 262144;
  j1.src[2] = wk_sel; j1.dst[2] = (unsigned*)(wqkvb + 1048576);         j1.n4[2] = 65536;
  j1.src[3] = wv_sel; j1.dst[3] = (unsigned*)(wqkvb + 1048576+262144);  j1.n4[3] = 65536;
  j1.src[4] = wk_win; j1.dst[4] = (unsigned*)(wqkvb + 1048576+524288);  j1.n4[4] = 65536;
  j1.src[5] = wv_win; j1.dst[5] = (unsigned*)(wqkvb + 1048576+786432);  j1.n4[5] = 65536;
  j1.src[6] = wk_cmp; j1.dst[6] = (unsigned*)(wqkvb + 1048576+1048576); j1.n4[6] = 65536;
  j1.src[7] = wv_cmp; j1.dst[7] = (unsigned*)(wqkvb + 1048576+1310720); j1.n4[7] = 65536;
  j1.src[8] = w_out;  j1.dst[8] = (unsigned*)w_outb;                    j1.n4[8] = 262144;
  conv_f32_bf16<<<1024, 256, 0, stream>>>(j1);

  // fused QKV projection: C[1024][2560] = x @ [wq;k/v weights]^T
  gemm_bf16<<<dim3(40, 16), 256, 0, stream>>>(xb, wqkvb, Cq, CSTR, 1024);

  // merged prep | transpose | pool
  mid_kernel<<<1600, 256, 0, stream>>>(Cq, g1w, g1b, g2w, g2b,
                                       q_b, kselb, kwinb, gts,
                                       vselT, vwinT, KcB, VcTB);

  // fused MFMA NSA attention (z=0: cmp+sel, z=1: win)
  attn_mfma_kernel<<<dim3(64, 4, 2), 256, 0, stream>>>(
      q_b, kselb, vselT, kwinb, vwinT, KcB, VcTB, gts, Ocs, Owin);

  // combine + output projection
  conv_add_bf16<<<1024, 256, 0, stream>>>(Ocs, Owin, (uint2*)xb);
  gemm_bf16<<<dim3(16, 16), 256, 0, stream>>>(xb, w_outb, (float*)d_out, 1024, 1024);
}